// Round 6
// baseline (562.519 us; speedup 1.0000x reference)
//
#include <hip/hip_runtime.h>

typedef unsigned short u16;
typedef __attribute__((ext_vector_type(4))) unsigned short u16x4;
typedef __attribute__((ext_vector_type(8))) unsigned short u16x8;
typedef __attribute__((ext_vector_type(8))) short s16x8;
typedef __attribute__((ext_vector_type(4))) float f32x4;

#define BATCH 16384
#define NFEAT 32
#define NVOCAB 50000

__device__ __forceinline__ u16 f2bf(float f) {
    union { float f; unsigned u; } v; v.f = f;
    unsigned u = v.u;
    return (u16)((u + 0x7fffu + ((u >> 16) & 1u)) >> 16);
}
__device__ __forceinline__ float bf2f(u16 h) {
    union { unsigned u; float f; } v; v.u = ((unsigned)h) << 16;
    return v.f;
}

__device__ __forceinline__ void load_lds16(const u16* g, u16* l) {
    __builtin_amdgcn_global_load_lds(
        (const __attribute__((address_space(1))) void*)g,
        (__attribute__((address_space(3))) void*)l, 16, 0, 0);
}

// ---------------------------------------------------------------------------
// Weight prep: fp32 [z][K][N] ->
//   frag==0: bf16 [z][N][K] (transposed, K-contiguous)  -- towers
//   frag==1: bf16 MFMA-fragment-linear [z][n>>4][k>>5][(k>>3)&3][n&15][k&7]
//            so one B-frag = contiguous 1KB, per-lane addr = base + lane*16B
// ---------------------------------------------------------------------------
struct PrepDesc { const float* src; u16* dst; int K; int N; int nz; int zbase; int frag; };
struct PrepArgs { PrepDesc d[6]; };

__global__ void prep_weights(PrepArgs args) {
    int z = blockIdx.z;
    int di = 0;
    #pragma unroll
    for (int i = 0; i < 6; i++)
        if (z >= args.d[i].zbase && z < args.d[i].zbase + args.d[i].nz) di = i;
    PrepDesc d = args.d[di];
    int zz = z - d.zbase;
    int k0 = blockIdx.x * 32, n0 = blockIdx.y * 32;
    if (k0 >= d.K || n0 >= d.N) return;
    __shared__ float tile[32][33];
    const float* src = d.src + (long)zz * d.K * d.N;
    u16* dst = d.dst + (long)zz * d.K * d.N;
    int tx = threadIdx.x & 31, ty = threadIdx.x >> 5;
    for (int r = ty; r < 32; r += 8) {
        int k = k0 + r, n = n0 + tx;
        tile[r][tx] = (k < d.K && n < d.N) ? src[(long)k * d.N + n] : 0.f;
    }
    __syncthreads();
    for (int r = ty; r < 32; r += 8) {
        int n = n0 + r, k = k0 + tx;
        if (n < d.N && k < d.K) {
            u16 v = f2bf(tile[tx][r]);
            if (d.frag) {
                long idx = (((long)(n >> 4) * (d.K >> 5) + (k >> 5)) * 4 + ((k >> 3) & 3)) * 128
                         + (long)(n & 15) * 8 + (k & 7);
                dst[idx] = v;
            } else {
                dst[(long)n * d.K + k] = v;
            }
        }
    }
}

// ---------------------------------------------------------------------------
// Embedding gather
// ---------------------------------------------------------------------------
__global__ void gather_embed(const int* __restrict__ ids,
                             const float* __restrict__ emb,
                             u16* __restrict__ out) {
    int idx = blockIdx.x * 256 + threadIdx.x;
    int d4 = idx & 3;
    int f  = (idx >> 2) & 31;
    int b  = idx >> 7;
    int id = ids[b * NFEAT + f];
    const float4* p = (const float4*)(emb + ((long)f * NVOCAB + id) * 16) + d4;
    float4 v = *p;
    u16x4 o;
    o.x = f2bf(v.x); o.y = f2bf(v.y); o.z = f2bf(v.z); o.w = f2bf(v.w);
    *(u16x4*)(out + (long)b * 512 + f * 16 + d4 * 4) = o;
}

// ---------------------------------------------------------------------------
// Fused two-layer expert, weights direct-from-L2 in fragment order:
//   O[z] = relu(relu(A[zsel] @ W1[z] + b1) @ W2[z] + b2)
// Per block: 64 rows. A staged to LDS ONCE (swizzled); W1/W2 B-frags read
// straight from global (L2-hot, fragment-linear -> coalesced 1KB/wave loads).
// H hand-off via swizzled sH. Barriers: 1 + 2/chunk = 9 per block (was 52).
// 4 waves, each owns 64 out-cols (stage2) / 32 H-cols per chunk (stage1).
// ---------------------------------------------------------------------------
struct FusedP {
    const u16* __restrict__ A; const u16* __restrict__ W1t; const float* __restrict__ b1;
    const u16* __restrict__ W2t; const float* __restrict__ b2; u16* __restrict__ O;
    int a_zshift; long a_zstride;
};

template<int NKT>   // K1/64: 8 for level-1 (K=512), 4 for level-2 (K=256)
__device__ __forceinline__ void expert_impl(const FusedP p) {
    __shared__ u16 sA[64 * 64 * NKT];   // 8KB per K-tile: 64KB (l1) / 32KB (l2)
    __shared__ u16 sH[64 * 128];        // 16KB H chunk, XOR-swizzled
    const int K1 = NKT * 64;
    const int z = blockIdx.z;
    const int m0 = blockIdx.x * 64;
    const u16* Ab  = p.A + (long)(z >> p.a_zshift) * p.a_zstride;
    const u16* W1f = p.W1t + (long)z * 512 * K1;   // frag-linear [32][K1/32][4][128]
    const u16* W2f = p.W2t + (long)z * 256 * 512;  // frag-linear [16][16][4][128]
    const int tid = threadIdx.x;
    const int lane = tid & 63;
    const int w = tid >> 6;           // 4 waves
    const int l16 = lane & 15;
    const int q = lane >> 4;
    const int key = l16 & 7;

    // per-thread fragment base: frag = base + q*128 + l16*8 (= lane*8)
    const u16* W1l = W1f + q * 128 + l16 * 8;
    const u16* W2l = W2f + q * 128 + l16 * 8;

    // ---- stage ALL of A once (swizzled via pre-swizzled source col) ----
    const int tr = tid >> 3;
    const int lc = (tid & 7) ^ (tr & 7);
    const u16* gA0 = Ab + (long)(m0 + tr) * K1 + lc * 8;
    const int ldst = (tid & ~63) * 8;
    #pragma unroll
    for (int kt = 0; kt < NKT; ++kt) {
        #pragma unroll
        for (int i = 0; i < 2; ++i)
            load_lds16(gA0 + (long)(32 * i) * K1 + kt * 64, &sA[kt * 4096 + i * 2048 + ldst]);
    }
    __syncthreads();

    f32x4 acc[4][4] = {};             // O acc: rows mt*16+l16, cols w*64+nt*16+q*4

    #pragma unroll
    for (int c = 0; c < 4; ++c) {
        f32x4 acc1[4][2] = {};        // H chunk acc: rows mt*16+l16, cols w*32+nt*16+q*4
        // ---- stage 1: H_c = A @ W1[:, c*128..+127]; B-frags from global ----
        #pragma unroll 2
        for (int kt = 0; kt < NKT; ++kt) {
            #pragma unroll
            for (int kk = 0; kk < 2; ++kk) {
                const int pc = ((kk << 2) | q) ^ key;
                s16x8 af[4], bf[2];
                #pragma unroll
                for (int mt = 0; mt < 4; ++mt)
                    af[mt] = *(const s16x8*)(&sA[kt * 4096 + (mt * 16 + l16) * 64 + pc * 8]);
                #pragma unroll
                for (int nt = 0; nt < 2; ++nt) {
                    const int ntile = c * 8 + w * 2 + nt;      // H-col tile (0..31)
                    const int ks = kt * 2 + kk;                // k32 index
                    bf[nt] = *(const s16x8*)(W1l + (((long)ntile * (NKT * 2) + ks) << 9));
                }
                #pragma unroll
                for (int mt = 0; mt < 4; ++mt)
                    #pragma unroll
                    for (int nt = 0; nt < 2; ++nt)
                        acc1[mt][nt] = __builtin_amdgcn_mfma_f32_16x16x32_bf16(
                            bf[nt], af[mt], acc1[mt][nt], 0, 0, 0);
            }
        }
        __syncthreads();              // all waves done reading sH (prev chunk stage2)
        // ---- H epilogue: bias + relu + bf16 -> swizzled sH ----
        {
            const float* bb1 = p.b1 + (long)z * 512 + c * 128;
            #pragma unroll
            for (int mt = 0; mt < 4; ++mt) {
                int r = mt * 16 + l16;
                #pragma unroll
                for (int nt = 0; nt < 2; ++nt) {
                    int col = w * 32 + nt * 16 + q * 4;
                    float4 bv = *(const float4*)(bb1 + col);
                    f32x4 v = acc1[mt][nt];
                    u16x4 o;
                    o.x = f2bf(fmaxf(v.x + bv.x, 0.f));
                    o.y = f2bf(fmaxf(v.y + bv.y, 0.f));
                    o.z = f2bf(fmaxf(v.z + bv.z, 0.f));
                    o.w = f2bf(fmaxf(v.w + bv.w, 0.f));
                    int c8 = col >> 3;
                    *(u16x4*)(&sH[r * 128 + ((c8 ^ (r & 7)) << 3) + (q & 1) * 4]) = o;
                }
            }
        }
        __syncthreads();              // sH visible
        // ---- stage 2: acc += H_c @ W2[c*128.., :]; B-frags from global ----
        #pragma unroll
        for (int s = 0; s < 2; ++s) {
            #pragma unroll
            for (int kk = 0; kk < 2; ++kk) {
                const int kg = s * 8 + ((kk << 2) | q);
                s16x8 af[4], bf[4];
                #pragma unroll
                for (int mt = 0; mt < 4; ++mt) {
                    int r = mt * 16 + l16;
                    af[mt] = *(const s16x8*)(&sH[r * 128 + ((kg ^ key) << 3)]);
                }
                #pragma unroll
                for (int nt = 0; nt < 4; ++nt) {
                    const int ntile = w * 4 + nt;              // out-col tile (0..15)
                    const int ks2 = c * 4 + s * 2 + kk;        // k32 index (0..15)
                    bf[nt] = *(const s16x8*)(W2l + (((long)ntile * 16 + ks2) << 9));
                }
                #pragma unroll
                for (int mt = 0; mt < 4; ++mt)
                    #pragma unroll
                    for (int nt = 0; nt < 4; ++nt)
                        acc[mt][nt] = __builtin_amdgcn_mfma_f32_16x16x32_bf16(
                            bf[nt], af[mt], acc[mt][nt], 0, 0, 0);
            }
        }
    }

    // ---- O epilogue ----
    const float* bb2 = p.b2 + (long)z * 256;
    u16* Op = p.O + (long)z * BATCH * 256;
    #pragma unroll
    for (int mt = 0; mt < 4; ++mt) {
        int grow = m0 + mt * 16 + l16;
        u16* rowp = Op + (long)grow * 256;
        #pragma unroll
        for (int nt = 0; nt < 4; ++nt) {
            int gc = w * 64 + nt * 16 + q * 4;
            float4 bv = *(const float4*)(bb2 + gc);
            f32x4 v = acc[mt][nt];
            v.x = fmaxf(v.x + bv.x, 0.f);
            v.y = fmaxf(v.y + bv.y, 0.f);
            v.z = fmaxf(v.z + bv.z, 0.f);
            v.w = fmaxf(v.w + bv.w, 0.f);
            u16x4 o;
            o.x = f2bf(v.x); o.y = f2bf(v.y); o.z = f2bf(v.z); o.w = f2bf(v.w);
            *(u16x4*)(rowp + gc) = o;
        }
    }
}

__global__ __launch_bounds__(256, 2) void fused_l1(FusedP p) { expert_impl<8>(p); }
__global__ __launch_bounds__(256, 2) void fused_l2(FusedP p) { expert_impl<4>(p); }

// ---------------------------------------------------------------------------
// Fused towers (unchanged)
// ---------------------------------------------------------------------------
__global__ __launch_bounds__(256, 1)
void tower_fused(const u16* __restrict__ x2, const u16* __restrict__ W1t,
                 const float* __restrict__ b1, const u16* __restrict__ W2t,
                 const float* __restrict__ b2, float* __restrict__ out) {
    const int t = blockIdx.y, m0 = blockIdx.x * 64;
    __shared__ u16 sX[64 * 256];
    __shared__ u16 sW1[128 * 256];
    __shared__ u16 sH[64 * 136];
    __shared__ u16 sW2[64 * 128];
    __shared__ float sB1[128];
    __shared__ float sB2[64];
    const int tid = threadIdx.x, lane = tid & 63, w = tid >> 6;
    const int l16 = lane & 15, q = lane >> 4;

    #pragma unroll
    for (int i = 0; i < 8; i++) {
        int c = i * 256 + tid, row = c >> 5, kc = c & 31;
        int lcc = (kc & ~7) | ((kc & 7) ^ (row & 7));
        load_lds16(x2 + ((long)t * BATCH + m0 + row) * 256 + lcc * 8,
                   &sX[(i * 256 + (tid & ~63)) * 8]);
    }
    #pragma unroll
    for (int i = 0; i < 16; i++) {
        int c = i * 256 + tid, row = c >> 5, kc = c & 31;
        int lcc = (kc & ~7) | ((kc & 7) ^ (row & 7));
        load_lds16(W1t + ((long)t * 128 + row) * 256 + lcc * 8,
                   &sW1[(i * 256 + (tid & ~63)) * 8]);
    }
    #pragma unroll
    for (int i = 0; i < 4; i++) {
        int c = i * 256 + tid, row = c >> 4, kc = c & 15;
        int lcc = (kc & ~7) | ((kc & 7) ^ (row & 7));
        load_lds16(W2t + ((long)t * 64 + row) * 128 + lcc * 8,
                   &sW2[(i * 256 + (tid & ~63)) * 8]);
    }
    if (tid < 128) sB1[tid] = b1[t * 128 + tid];
    if (tid < 64)  sB2[tid] = b2[t * 64 + tid];
    __syncthreads();

    f32x4 acc1[4][2] = {};
    #pragma unroll
    for (int kk = 0; kk < 8; kk++) {
        int pcb = kk * 4 + q;
        s16x8 af[4], bf[2];
        #pragma unroll
        for (int mt = 0; mt < 4; mt++) {
            int row = mt * 16 + l16;
            int sc = (pcb & ~7) | ((pcb & 7) ^ (row & 7));
            af[mt] = *(const s16x8*)(&sX[row * 256 + sc * 8]);
        }
        #pragma unroll
        for (int nt = 0; nt < 2; nt++) {
            int row = w * 32 + nt * 16 + l16;
            int sc = (pcb & ~7) | ((pcb & 7) ^ (row & 7));
            bf[nt] = *(const s16x8*)(&sW1[row * 256 + sc * 8]);
        }
        #pragma unroll
        for (int mt = 0; mt < 4; mt++)
            #pragma unroll
            for (int nt = 0; nt < 2; nt++)
                acc1[mt][nt] = __builtin_amdgcn_mfma_f32_16x16x32_bf16(
                    bf[nt], af[mt], acc1[mt][nt], 0, 0, 0);
    }
    #pragma unroll
    for (int mt = 0; mt < 4; mt++) {
        int row = mt * 16 + l16;
        #pragma unroll
        for (int nt = 0; nt < 2; nt++) {
            int col = w * 32 + nt * 16 + q * 4;
            f32x4 v = acc1[mt][nt];
            u16x4 o;
            o.x = f2bf(fmaxf(v.x + sB1[col + 0], 0.f));
            o.y = f2bf(fmaxf(v.y + sB1[col + 1], 0.f));
            o.z = f2bf(fmaxf(v.z + sB1[col + 2], 0.f));
            o.w = f2bf(fmaxf(v.w + sB1[col + 3], 0.f));
            *(u16x4*)(&sH[row * 136 + col]) = o;
        }
    }
    __syncthreads();

    f32x4 acc2[4] = {};
    #pragma unroll
    for (int kk = 0; kk < 4; kk++) {
        s16x8 af[4], bf;
        #pragma unroll
        for (int mt = 0; mt < 4; mt++) {
            int row = mt * 16 + l16;
            af[mt] = *(const s16x8*)(&sH[row * 136 + kk * 32 + q * 8]);
        }
        {
            int row = w * 16 + l16;
            int pc = kk * 4 + q;
            int sc = (pc & ~7) | ((pc & 7) ^ (row & 7));
            bf = *(const s16x8*)(&sW2[row * 128 + sc * 8]);
        }
        #pragma unroll
        for (int mt = 0; mt < 4; mt++)
            acc2[mt] = __builtin_amdgcn_mfma_f32_16x16x32_bf16(
                bf, af[mt], acc2[mt], 0, 0, 0);
    }
    #pragma unroll
    for (int mt = 0; mt < 4; mt++) {
        int grow = m0 + mt * 16 + l16;
        int col = w * 16 + q * 4;
        float4 bv = *(const float4*)(sB2 + col);
        f32x4 v = acc2[mt];
        float4 r;
        r.x = 1.f / (1.f + __expf(-(v.x + bv.x)));
        r.y = 1.f / (1.f + __expf(-(v.y + bv.y)));
        r.z = 1.f / (1.f + __expf(-(v.z + bv.z)));
        r.w = 1.f / (1.f + __expf(-(v.w + bv.w)));
        *(float4*)(out + (long)grow * 128 + t * 64 + col) = r;
    }
}

// ---------------------------------------------------------------------------
// Level-1 fused gates+combine (unchanged)
// ---------------------------------------------------------------------------
__global__ __launch_bounds__(256)
void gate1(const u16* __restrict__ embed, const u16* __restrict__ out1,
           const float* __restrict__ g1Ws, const float* __restrict__ g1bs,
           const float* __restrict__ gWsh, const float* __restrict__ gbsh,
           u16* __restrict__ x1) {
    const int m0 = blockIdx.x * 8;
    __shared__ float sg[8][16];
    const int tid = threadIdx.x;
    const int row = tid >> 5, l = tid & 31;
    const long rb = m0 + row;

    float a[4] = {0,0,0,0}, b[4] = {0,0,0,0}, c[6] = {0,0,0,0,0,0};
    {
        const u16* er = embed + rb * 512 + l * 16;
        u16x8 xa = *(const u16x8*)(er);
        u16x8 xb = *(const u16x8*)(er + 8);
        #pragma unroll
        for (int u = 0; u < 16; u++) {
            int k = l * 16 + u;
            float xv = bf2f(u < 8 ? xa[u] : xb[u - 8]);
            float4 wa = *(const float4*)(g1Ws + k * 4);
            float4 wb = *(const float4*)(g1Ws + 2048 + k * 4);
            a[0] += xv * wa.x; a[1] += xv * wa.y; a[2] += xv * wa.z; a[3] += xv * wa.w;
            b[0] += xv * wb.x; b[1] += xv * wb.y; b[2] += xv * wb.z; b[3] += xv * wb.w;
            float2 w0 = *(const float2*)(gWsh + k * 6);
            float2 w1 = *(const float2*)(gWsh + k * 6 + 2);
            float2 w2 = *(const float2*)(gWsh + k * 6 + 4);
            c[0] += xv * w0.x; c[1] += xv * w0.y;
            c[2] += xv * w1.x; c[3] += xv * w1.y;
            c[4] += xv * w2.x; c[5] += xv * w2.y;
        }
    }
    #pragma unroll
    for (int off = 1; off < 32; off <<= 1) {
        #pragma unroll
        for (int g = 0; g < 4; g++) { a[g] += __shfl_xor(a[g], off); b[g] += __shfl_xor(b[g], off); }
        #pragma unroll
        for (int g = 0; g < 6; g++) c[g] += __shfl_xor(c[g], off);
    }
    if (l == 0) {
        float mx, s, e[6];
        mx = -1e30f;
        for (int g = 0; g < 4; g++) { a[g] += g1bs[g]; mx = fmaxf(mx, a[g]); }
        s = 0.f; for (int g = 0; g < 4; g++) { e[g] = __expf(a[g] - mx); s += e[g]; }
        for (int g = 0; g < 4; g++) sg[row][g] = e[g] / s;
        mx = -1e30f;
        for (int g = 0; g < 4; g++) { b[g] += g1bs[4 + g]; mx = fmaxf(mx, b[g]); }
        s = 0.f; for (int g = 0; g < 4; g++) { e[g] = __expf(b[g] - mx); s += e[g]; }
        for (int g = 0; g < 4; g++) sg[row][4 + g] = e[g] / s;
        mx = -1e30f;
        for (int g = 0; g < 6; g++) { c[g] += gbsh[g]; mx = fmaxf(mx, c[g]); }
        s = 0.f; for (int g = 0; g < 6; g++) { e[g] = __expf(c[g] - mx); s += e[g]; }
        for (int g = 0; g < 6; g++) sg[row][8 + g] = e[g] / s;
    }
    __syncthreads();

    const int c8 = l * 8;
    const u16* ob = out1 + rb * 256 + c8;
    u16x8 o[6];
    #pragma unroll
    for (int k = 0; k < 6; k++) o[k] = *(const u16x8*)(ob + (long)k * BATCH * 256);
    const float* g = sg[row];
    u16x8 r0, r1, r2;
    #pragma unroll
    for (int u = 0; u < 8; u++) {
        float o0 = bf2f(o[0][u]), o1 = bf2f(o[1][u]), o2 = bf2f(o[2][u]);
        float o3 = bf2f(o[3][u]), o4 = bf2f(o[4][u]), o5 = bf2f(o[5][u]);
        r0[u] = f2bf(g[0] * o0 + g[1] * o1 + g[2] * o4 + g[3] * o5);
        r1[u] = f2bf(g[4] * o2 + g[5] * o3 + g[6] * o4 + g[7] * o5);
        r2[u] = f2bf(g[8] * o0 + g[9] * o1 + g[10] * o2 + g[11] * o3 + g[12] * o4 + g[13] * o5);
    }
    *(u16x8*)(x1 + ((long)0 * BATCH + rb) * 256 + c8) = r0;
    *(u16x8*)(x1 + ((long)1 * BATCH + rb) * 256 + c8) = r1;
    *(u16x8*)(x1 + ((long)2 * BATCH + rb) * 256 + c8) = r2;
}

// ---------------------------------------------------------------------------
// Level-2 fused gates+combine (unchanged)
// ---------------------------------------------------------------------------
__global__ __launch_bounds__(256)
void gate2(const u16* __restrict__ x1, const u16* __restrict__ out2,
           const float* __restrict__ g2Ws, const float* __restrict__ g2bs,
           u16* __restrict__ x2) {
    const int m0 = blockIdx.x * 8;
    __shared__ float sg[8][8];
    const int tid = threadIdx.x;
    const int row = tid >> 5, l = tid & 31;
    const long rb = m0 + row;

    float a[4] = {0,0,0,0}, b[4] = {0,0,0,0};
    {
        const u16* e0 = x1 + rb * 256 + l * 8;
        const u16* e1 = e0 + (long)BATCH * 256;
        u16x8 x0 = *(const u16x8*)e0;
        u16x8 x1v = *(const u16x8*)e1;
        #pragma unroll
        for (int u = 0; u < 8; u++) {
            int k = l * 8 + u;
            float4 wa = *(const float4*)(g2Ws + k * 4);
            float4 wb = *(const float4*)(g2Ws + 1024 + k * 4);
            float xv0 = bf2f(x0[u]), xv1 = bf2f(x1v[u]);
            a[0] += xv0 * wa.x; a[1] += xv0 * wa.y; a[2] += xv0 * wa.z; a[3] += xv0 * wa.w;
            b[0] += xv1 * wb.x; b[1] += xv1 * wb.y; b[2] += xv1 * wb.z; b[3] += xv1 * wb.w;
        }
    }
    #pragma unroll
    for (int off = 1; off < 32; off <<= 1) {
        #pragma unroll
        for (int g = 0; g < 4; g++) { a[g] += __shfl_xor(a[g], off); b[g] += __shfl_xor(b[g], off); }
    }
    if (l == 0) {
        float mx, s, e[4];
        mx = -1e30f;
        for (int g = 0; g < 4; g++) { a[g] += g2bs[g]; mx = fmaxf(mx, a[g]); }
        s = 0.f; for (int g = 0; g < 4; g++) { e[g] = __expf(a[g] - mx); s += e[g]; }
        for (int g = 0; g < 4; g++) sg[row][g] = e[g] / s;
        mx = -1e30f;
        for (int g = 0; g < 4; g++) { b[g] += g2bs[4 + g]; mx = fmaxf(mx, b[g]); }
        s = 0.f; for (int g = 0; g < 4; g++) { e[g] = __expf(b[g] - mx); s += e[g]; }
        for (int g = 0; g < 4; g++) sg[row][4 + g] = e[g] / s;
    }
    __syncthreads();

    const int c8 = l * 8;
    const u16* ob = out2 + rb * 256 + c8;
    u16x8 o[6];
    #pragma unroll
    for (int k = 0; k < 6; k++) o[k] = *(const u16x8*)(ob + (long)k * BATCH * 256);
    const float* g = sg[row];
    u16x8 r0, r1;
    #pragma unroll
    for (int u = 0; u < 8; u++) {
        float o0 = bf2f(o[0][u]), o1 = bf2f(o[1][u]), o2 = bf2f(o[2][u]);
        float o3 = bf2f(o[3][u]), o4 = bf2f(o[4][u]), o5 = bf2f(o[5][u]);
        r0[u] = f2bf(g[0] * o0 + g[1] * o1 + g[2] * o4 + g[3] * o5);
        r1[u] = f2bf(g[4] * o2 + g[5] * o3 + g[6] * o4 + g[7] * o5);
    }
    *(u16x8*)(x2 + ((long)0 * BATCH + rb) * 256 + c8) = r0;
    *(u16x8*)(x2 + ((long)1 * BATCH + rb) * 256 + c8) = r1;
}

// ---------------------------------------------------------------------------
extern "C" void kernel_launch(void* const* d_in, const int* in_sizes, int n_in,
                              void* d_out, int out_size, void* d_ws, size_t ws_size,
                              hipStream_t stream) {
    const int*   x_ids = (const int*)  d_in[0];
    const float* emb   = (const float*)d_in[1];
    const float* e1W1  = (const float*)d_in[2];
    const float* e1b1  = (const float*)d_in[3];
    const float* e1W2  = (const float*)d_in[4];
    const float* e1b2  = (const float*)d_in[5];
    const float* g1Ws  = (const float*)d_in[6];
    const float* g1bs  = (const float*)d_in[7];
    const float* g1Wsh = (const float*)d_in[8];
    const float* g1bsh = (const float*)d_in[9];
    const float* e2W1  = (const float*)d_in[10];
    const float* e2b1  = (const float*)d_in[11];
    const float* e2W2  = (const float*)d_in[12];
    const float* e2b2  = (const float*)d_in[13];
    const float* g2Ws  = (const float*)d_in[14];
    const float* g2bs  = (const float*)d_in[15];
    const float* twW1  = (const float*)d_in[16];
    const float* twb1  = (const float*)d_in[17];
    const float* twW2  = (const float*)d_in[18];
    const float* twb2  = (const float*)d_in[19];
    float* out = (float*)d_out;

    char* ws = (char*)d_ws;
    u16* embed   = (u16*)(ws + 0);                       // [B,512]
    u16* wt_e1W1 = (u16*)(ws + 16777216);                // [6,512,512] frag
    u16* wt_e1W2 = (u16*)(ws + 19922944);                // [6,256,512] frag
    u16* wt_e2W1 = (u16*)(ws + 21495808);                // [6,512,256] frag
    u16* wt_e2W2 = (u16*)(ws + 23068672);                // [6,256,512] frag
    u16* wt_twW1 = (u16*)(ws + 24641536);                // [2,128,256]
    u16* wt_twW2 = (u16*)(ws + 24772608);                // [2,64,128]
    u16* o_buf   = (u16*)(ws + 125468672);               // [6,B,256]
    u16* x1      = (u16*)(ws + 175800320);               // [3,B,256]
    u16* x2      = (u16*)(ws + 200966144);               // [2,B,256]

    PrepArgs pa;
    pa.d[0] = { e1W1, wt_e1W1, 512, 512, 6,  0, 1 };
    pa.d[1] = { e1W2, wt_e1W2, 512, 256, 6,  6, 1 };
    pa.d[2] = { e2W1, wt_e2W1, 256, 512, 6, 12, 1 };
    pa.d[3] = { e2W2, wt_e2W2, 512, 256, 6, 18, 1 };
    pa.d[4] = { twW1, wt_twW1, 256, 128, 2, 24, 0 };
    pa.d[5] = { twW2, wt_twW2, 128,  64, 2, 26, 0 };
    prep_weights<<<dim3(16, 16, 28), 256, 0, stream>>>(pa);

    gather_embed<<<dim3(BATCH * NFEAT * 4 / 256), 256, 0, stream>>>(x_ids, emb, embed);

    // Level 1: fused two-layer experts, weights from L2 in frag order
    FusedP f1 = { embed, wt_e1W1, e1b1, wt_e1W2, e1b2, o_buf, 3, 0L };
    fused_l1<<<dim3(BATCH / 64, 1, 6), 256, 0, stream>>>(f1);

    gate1<<<dim3(BATCH / 8), 256, 0, stream>>>(embed, o_buf, g1Ws, g1bs, g1Wsh, g1bsh, x1);

    // Level 2
    FusedP f2 = { x1, wt_e2W1, e2b1, wt_e2W2, e2b2, o_buf, 1, (long)BATCH * 256 };
    fused_l2<<<dim3(BATCH / 64, 1, 6), 256, 0, stream>>>(f2);

    gate2<<<dim3(BATCH / 8), 256, 0, stream>>>(x1, o_buf, g2Ws, g2bs, x2);

    tower_fused<<<dim3(BATCH / 64, 2), 256, 0, stream>>>(x2, wt_twW1, twb1, wt_twW2, twb2, out);
}

// Round 7
// 528.268 us; speedup vs baseline: 1.0648x; 1.0648x over previous
//
#include <hip/hip_runtime.h>

typedef unsigned short u16;
typedef __attribute__((ext_vector_type(4))) unsigned short u16x4;
typedef __attribute__((ext_vector_type(8))) unsigned short u16x8;
typedef __attribute__((ext_vector_type(8))) short s16x8;
typedef __attribute__((ext_vector_type(4))) float f32x4;

#define BATCH 16384
#define NFEAT 32
#define NVOCAB 50000

__device__ __forceinline__ u16 f2bf(float f) {
    union { float f; unsigned u; } v; v.f = f;
    unsigned u = v.u;
    return (u16)((u + 0x7fffu + ((u >> 16) & 1u)) >> 16);
}
__device__ __forceinline__ float bf2f(u16 h) {
    union { unsigned u; float f; } v; v.u = ((unsigned)h) << 16;
    return v.f;
}

__device__ __forceinline__ void load_lds16(const u16* g, u16* l) {
    __builtin_amdgcn_global_load_lds(
        (const __attribute__((address_space(1))) void*)g,
        (__attribute__((address_space(3))) void*)l, 16, 0, 0);
}

// ---------------------------------------------------------------------------
// Weight prep: fp32 [z][K][N] -> bf16 [z][N][K] (transposed, K-contiguous)
// ---------------------------------------------------------------------------
struct PrepDesc { const float* src; u16* dst; int K; int N; int nz; int zbase; };
struct PrepArgs { PrepDesc d[6]; };

__global__ void prep_weights(PrepArgs args) {
    int z = blockIdx.z;
    int di = 0;
    #pragma unroll
    for (int i = 0; i < 6; i++)
        if (z >= args.d[i].zbase && z < args.d[i].zbase + args.d[i].nz) di = i;
    PrepDesc d = args.d[di];
    int zz = z - d.zbase;
    int k0 = blockIdx.x * 32, n0 = blockIdx.y * 32;
    if (k0 >= d.K || n0 >= d.N) return;
    __shared__ float tile[32][33];
    const float* src = d.src + (long)zz * d.K * d.N;
    u16* dst = d.dst + (long)zz * d.K * d.N;
    int tx = threadIdx.x & 31, ty = threadIdx.x >> 5;
    for (int r = ty; r < 32; r += 8) {
        int k = k0 + r, n = n0 + tx;
        tile[r][tx] = (k < d.K && n < d.N) ? src[(long)k * d.N + n] : 0.f;
    }
    __syncthreads();
    for (int r = ty; r < 32; r += 8) {
        int n = n0 + r, k = k0 + tx;
        if (n < d.N && k < d.K) dst[(long)n * d.K + k] = f2bf(tile[tx][r]);
    }
}

// ---------------------------------------------------------------------------
// Embedding gather
// ---------------------------------------------------------------------------
__global__ void gather_embed(const int* __restrict__ ids,
                             const float* __restrict__ emb,
                             u16* __restrict__ out) {
    int idx = blockIdx.x * 256 + threadIdx.x;
    int d4 = idx & 3;
    int f  = (idx >> 2) & 31;
    int b  = idx >> 7;
    int id = ids[b * NFEAT + f];
    const float4* p = (const float4*)(emb + ((long)f * NVOCAB + id) * 16) + d4;
    float4 v = *p;
    u16x4 o;
    o.x = f2bf(v.x); o.y = f2bf(v.y); o.z = f2bf(v.z); o.w = f2bf(v.w);
    *(u16x4*)(out + (long)b * 512 + f * 16 + d4 * 4) = o;
}

// ---------------------------------------------------------------------------
// MEGA level-1: per block 32 rows; gates (14 coefs) computed in-kernel; loop
// over all 6 experts with the proven two-stage structure; expert outputs
// folded (bias+relu+gate-scale) into persistent f32 combined accumulators;
// writes x1[0..2] directly. o_buf and gate1 eliminated.
// LDS: sA 4KB + sW 32KB + sH 16KB + sg ~2KB  -> 2 blocks/CU.
// ---------------------------------------------------------------------------
struct MegaP1 {
    const u16* A; const u16* W1; const u16* W2;
    const float* b1; const float* b2;
    const float* gWs; const float* gbs; const float* gWsh; const float* gbsh;
    u16* x1;
};

__global__ __launch_bounds__(256, 2)
void mega_l1(MegaP1 p) {
    __shared__ u16 sA[2048];          // 32 x 64 (current k-tile)
    __shared__ u16 sW[16384];         // 256 x 64 (current W tile)
    __shared__ u16 sH[8192];          // 32 x 256 H chunk (swizzled)
    __shared__ float sg[32][17];      // 14 gate coefs per row (padded)
    const int m0 = blockIdx.x * 32;
    const int tid = threadIdx.x;
    const int lane = tid & 63;
    const int w = tid >> 6;
    const int l16 = lane & 15;
    const int q = lane >> 4;
    const int key = l16 & 7;

    // ---------------- gates (transplanted gate1 math, 8 lanes/row) --------
    {
        const int row = tid >> 3, l8 = tid & 7;
        const long rb = m0 + row;
        float a[4] = {0,0,0,0}, b[4] = {0,0,0,0}, c[6] = {0,0,0,0,0,0};
        const u16* er = p.A + rb * 512 + l8 * 64;
        #pragma unroll
        for (int v = 0; v < 8; v++) {
            u16x8 xv8 = *(const u16x8*)(er + v * 8);
            #pragma unroll
            for (int u = 0; u < 8; u++) {
                int k = l8 * 64 + v * 8 + u;
                float xv = bf2f(xv8[u]);
                float4 wa = *(const float4*)(p.gWs + k * 4);
                float4 wb = *(const float4*)(p.gWs + 2048 + k * 4);
                a[0] += xv * wa.x; a[1] += xv * wa.y; a[2] += xv * wa.z; a[3] += xv * wa.w;
                b[0] += xv * wb.x; b[1] += xv * wb.y; b[2] += xv * wb.z; b[3] += xv * wb.w;
                float2 w0 = *(const float2*)(p.gWsh + k * 6);
                float2 w1 = *(const float2*)(p.gWsh + k * 6 + 2);
                float2 w2 = *(const float2*)(p.gWsh + k * 6 + 4);
                c[0] += xv * w0.x; c[1] += xv * w0.y;
                c[2] += xv * w1.x; c[3] += xv * w1.y;
                c[4] += xv * w2.x; c[5] += xv * w2.y;
            }
        }
        #pragma unroll
        for (int off = 1; off < 8; off <<= 1) {
            #pragma unroll
            for (int g = 0; g < 4; g++) { a[g] += __shfl_xor(a[g], off); b[g] += __shfl_xor(b[g], off); }
            #pragma unroll
            for (int g = 0; g < 6; g++) c[g] += __shfl_xor(c[g], off);
        }
        if (l8 == 0) {
            float mx, s, e[6];
            mx = -1e30f;
            for (int g = 0; g < 4; g++) { a[g] += p.gbs[g]; mx = fmaxf(mx, a[g]); }
            s = 0.f; for (int g = 0; g < 4; g++) { e[g] = __expf(a[g] - mx); s += e[g]; }
            for (int g = 0; g < 4; g++) sg[row][g] = e[g] / s;
            mx = -1e30f;
            for (int g = 0; g < 4; g++) { b[g] += p.gbs[4 + g]; mx = fmaxf(mx, b[g]); }
            s = 0.f; for (int g = 0; g < 4; g++) { e[g] = __expf(b[g] - mx); s += e[g]; }
            for (int g = 0; g < 4; g++) sg[row][4 + g] = e[g] / s;
            mx = -1e30f;
            for (int g = 0; g < 6; g++) { c[g] += p.gbsh[g]; mx = fmaxf(mx, c[g]); }
            s = 0.f; for (int g = 0; g < 6; g++) { e[g] = __expf(c[g] - mx); s += e[g]; }
            for (int g = 0; g < 6; g++) sg[row][8 + g] = e[g] / s;
        }
    }
    __syncthreads();

    const int tr = tid >> 3;
    const int lc = (tid & 7) ^ (tr & 7);
    const u16* gA = p.A + (long)(m0 + tr) * 512 + lc * 8;
    const int ldst = (tid & ~63) * 8;

    f32x4 comb0[2][4] = {}, comb1[2][4] = {}, combs[2][4] = {};

    for (int z = 0; z < 6; ++z) {
        const u16* W1b = p.W1 + (long)z * 512 * 512;
        const u16* W2b = p.W2 + (long)z * 256 * 512;
        f32x4 acc[2][4] = {};
        #pragma unroll
        for (int c = 0; c < 2; ++c) {
            f32x4 acc1[2][4] = {};
            for (int kt = 0; kt < 8; ++kt) {
                __syncthreads();
                load_lds16(gA + kt * 64, &sA[ldst]);
                #pragma unroll
                for (int i = 0; i < 8; i++)
                    load_lds16(W1b + (long)(c * 256 + 32 * i + tr) * 512 + kt * 64 + lc * 8,
                               &sW[i * 2048 + ldst]);
                __syncthreads();
                #pragma unroll
                for (int kk = 0; kk < 2; ++kk) {
                    const int pc = ((kk << 2) | q) ^ key;
                    s16x8 af[2], bf[4];
                    #pragma unroll
                    for (int mt = 0; mt < 2; ++mt)
                        af[mt] = *(const s16x8*)(&sA[(mt * 16 + l16) * 64 + pc * 8]);
                    #pragma unroll
                    for (int nt = 0; nt < 4; ++nt)
                        bf[nt] = *(const s16x8*)(&sW[(w * 64 + nt * 16 + l16) * 64 + pc * 8]);
                    #pragma unroll
                    for (int mt = 0; mt < 2; ++mt)
                        #pragma unroll
                        for (int nt = 0; nt < 4; ++nt)
                            acc1[mt][nt] = __builtin_amdgcn_mfma_f32_16x16x32_bf16(
                                bf[nt], af[mt], acc1[mt][nt], 0, 0, 0);
                }
            }
            __syncthreads();
            // H epilogue: bias + relu + bf16 -> swizzled sH (32 x 256)
            {
                const float* bb1 = p.b1 + (long)z * 512 + c * 256;
                #pragma unroll
                for (int mt = 0; mt < 2; ++mt) {
                    int r = mt * 16 + l16;
                    #pragma unroll
                    for (int nt = 0; nt < 4; ++nt) {
                        int col = w * 64 + nt * 16 + q * 4;
                        float4 bv = *(const float4*)(bb1 + col);
                        f32x4 v = acc1[mt][nt];
                        u16x4 o;
                        o.x = f2bf(fmaxf(v.x + bv.x, 0.f));
                        o.y = f2bf(fmaxf(v.y + bv.y, 0.f));
                        o.z = f2bf(fmaxf(v.z + bv.z, 0.f));
                        o.w = f2bf(fmaxf(v.w + bv.w, 0.f));
                        int grp = col >> 3;                   // 0..31
                        *(u16x4*)(&sH[r * 256 + ((grp ^ (r & 7)) << 3) + (q & 1) * 4]) = o;
                    }
                }
            }
            // stage 2: acc += H_c @ W2[c*256.., :]
            #pragma unroll
            for (int s = 0; s < 4; ++s) {
                __syncthreads();
                #pragma unroll
                for (int i = 0; i < 8; i++)
                    load_lds16(W2b + (long)(32 * i + tr) * 512 + c * 256 + s * 64 + lc * 8,
                               &sW[i * 2048 + ldst]);
                __syncthreads();
                #pragma unroll
                for (int kk = 0; kk < 2; ++kk) {
                    const int pc = ((kk << 2) | q) ^ key;
                    const int kg = s * 8 + ((kk << 2) | q);
                    s16x8 af[2], bf[4];
                    #pragma unroll
                    for (int mt = 0; mt < 2; ++mt) {
                        int r = mt * 16 + l16;
                        af[mt] = *(const s16x8*)(&sH[r * 256 + ((kg ^ key) << 3)]);
                    }
                    #pragma unroll
                    for (int nt = 0; nt < 4; ++nt)
                        bf[nt] = *(const s16x8*)(&sW[(w * 64 + nt * 16 + l16) * 64 + pc * 8]);
                    #pragma unroll
                    for (int mt = 0; mt < 2; ++mt)
                        #pragma unroll
                        for (int nt = 0; nt < 4; ++nt)
                            acc[mt][nt] = __builtin_amdgcn_mfma_f32_16x16x32_bf16(
                                bf[nt], af[mt], acc[mt][nt], 0, 0, 0);
                }
            }
        }
        // fold: O_z = relu(acc + b2), comb += gate * O_z
        #pragma unroll
        for (int mt = 0; mt < 2; ++mt) {
            int r = mt * 16 + l16;
            const float* g = sg[r];
            float c0 = (z == 0) ? g[0] : (z == 1) ? g[1] : (z == 4) ? g[2] : (z == 5) ? g[3] : 0.f;
            float c1 = (z == 2) ? g[4] : (z == 3) ? g[5] : (z == 4) ? g[6] : (z == 5) ? g[7] : 0.f;
            float cs = g[8 + z];
            #pragma unroll
            for (int nt = 0; nt < 4; ++nt) {
                int gc = w * 64 + nt * 16 + q * 4;
                float4 bv = *(const float4*)(p.b2 + (long)z * 256 + gc);
                f32x4 v = acc[mt][nt];
                v.x = fmaxf(v.x + bv.x, 0.f);
                v.y = fmaxf(v.y + bv.y, 0.f);
                v.z = fmaxf(v.z + bv.z, 0.f);
                v.w = fmaxf(v.w + bv.w, 0.f);
                comb0[mt][nt] += v * c0;
                comb1[mt][nt] += v * c1;
                combs[mt][nt] += v * cs;
            }
        }
    }

    // epilogue: write x1[0], x1[1], x1[2]
    #pragma unroll
    for (int mt = 0; mt < 2; ++mt) {
        long grow = m0 + mt * 16 + l16;
        #pragma unroll
        for (int nt = 0; nt < 4; ++nt) {
            int gc = w * 64 + nt * 16 + q * 4;
            u16x4 o;
            f32x4 v = comb0[mt][nt];
            o.x = f2bf(v.x); o.y = f2bf(v.y); o.z = f2bf(v.z); o.w = f2bf(v.w);
            *(u16x4*)(p.x1 + ((long)0 * BATCH + grow) * 256 + gc) = o;
            v = comb1[mt][nt];
            o.x = f2bf(v.x); o.y = f2bf(v.y); o.z = f2bf(v.z); o.w = f2bf(v.w);
            *(u16x4*)(p.x1 + ((long)1 * BATCH + grow) * 256 + gc) = o;
            v = combs[mt][nt];
            o.x = f2bf(v.x); o.y = f2bf(v.y); o.z = f2bf(v.z); o.w = f2bf(v.w);
            *(u16x4*)(p.x1 + ((long)2 * BATCH + grow) * 256 + gc) = o;
        }
    }
}

// ---------------------------------------------------------------------------
// MEGA level-2: same structure, K=256, A slice per expert-pair (x1[z>>1]),
// 8 gate coefs (2 tasks), writes x2[0..1]. o_buf and gate2 eliminated.
// ---------------------------------------------------------------------------
struct MegaP2 {
    const u16* x1; const u16* W1; const u16* W2;
    const float* b1; const float* b2;
    const float* gWs; const float* gbs;
    u16* x2;
};

__global__ __launch_bounds__(256, 2)
void mega_l2(MegaP2 p) {
    __shared__ u16 sA[2048];
    __shared__ u16 sW[16384];
    __shared__ u16 sH[8192];
    __shared__ float sg[32][17];
    const int m0 = blockIdx.x * 32;
    const int tid = threadIdx.x;
    const int lane = tid & 63;
    const int w = tid >> 6;
    const int l16 = lane & 15;
    const int q = lane >> 4;
    const int key = l16 & 7;

    // ---------------- gates (transplanted gate2 math, 8 lanes/row) --------
    {
        const int row = tid >> 3, l8 = tid & 7;
        const long rb = m0 + row;
        float a[4] = {0,0,0,0}, b[4] = {0,0,0,0};
        const u16* e0 = p.x1 + rb * 256 + l8 * 32;
        const u16* e1 = e0 + (long)BATCH * 256;
        #pragma unroll
        for (int v = 0; v < 4; v++) {
            u16x8 x0 = *(const u16x8*)(e0 + v * 8);
            u16x8 x1v = *(const u16x8*)(e1 + v * 8);
            #pragma unroll
            for (int u = 0; u < 8; u++) {
                int k = l8 * 32 + v * 8 + u;
                float4 wa = *(const float4*)(p.gWs + k * 4);
                float4 wb = *(const float4*)(p.gWs + 1024 + k * 4);
                float xv0 = bf2f(x0[u]), xv1 = bf2f(x1v[u]);
                a[0] += xv0 * wa.x; a[1] += xv0 * wa.y; a[2] += xv0 * wa.z; a[3] += xv0 * wa.w;
                b[0] += xv1 * wb.x; b[1] += xv1 * wb.y; b[2] += xv1 * wb.z; b[3] += xv1 * wb.w;
            }
        }
        #pragma unroll
        for (int off = 1; off < 8; off <<= 1) {
            #pragma unroll
            for (int g = 0; g < 4; g++) { a[g] += __shfl_xor(a[g], off); b[g] += __shfl_xor(b[g], off); }
        }
        if (l8 == 0) {
            float mx, s, e[4];
            mx = -1e30f;
            for (int g = 0; g < 4; g++) { a[g] += p.gbs[g]; mx = fmaxf(mx, a[g]); }
            s = 0.f; for (int g = 0; g < 4; g++) { e[g] = __expf(a[g] - mx); s += e[g]; }
            for (int g = 0; g < 4; g++) sg[row][g] = e[g] / s;
            mx = -1e30f;
            for (int g = 0; g < 4; g++) { b[g] += p.gbs[4 + g]; mx = fmaxf(mx, b[g]); }
            s = 0.f; for (int g = 0; g < 4; g++) { e[g] = __expf(b[g] - mx); s += e[g]; }
            for (int g = 0; g < 4; g++) sg[row][4 + g] = e[g] / s;
        }
    }
    __syncthreads();

    const int tr = tid >> 3;
    const int lc = (tid & 7) ^ (tr & 7);
    const int ldst = (tid & ~63) * 8;

    f32x4 comb0[2][4] = {}, comb1[2][4] = {};

    for (int z = 0; z < 6; ++z) {
        const u16* gA = p.x1 + ((long)(z >> 1) * BATCH + m0 + tr) * 256 + lc * 8;
        const u16* W1b = p.W1 + (long)z * 512 * 256;
        const u16* W2b = p.W2 + (long)z * 256 * 512;
        f32x4 acc[2][4] = {};
        #pragma unroll
        for (int c = 0; c < 2; ++c) {
            f32x4 acc1[2][4] = {};
            for (int kt = 0; kt < 4; ++kt) {
                __syncthreads();
                load_lds16(gA + kt * 64, &sA[ldst]);
                #pragma unroll
                for (int i = 0; i < 8; i++)
                    load_lds16(W1b + (long)(c * 256 + 32 * i + tr) * 256 + kt * 64 + lc * 8,
                               &sW[i * 2048 + ldst]);
                __syncthreads();
                #pragma unroll
                for (int kk = 0; kk < 2; ++kk) {
                    const int pc = ((kk << 2) | q) ^ key;
                    s16x8 af[2], bf[4];
                    #pragma unroll
                    for (int mt = 0; mt < 2; ++mt)
                        af[mt] = *(const s16x8*)(&sA[(mt * 16 + l16) * 64 + pc * 8]);
                    #pragma unroll
                    for (int nt = 0; nt < 4; ++nt)
                        bf[nt] = *(const s16x8*)(&sW[(w * 64 + nt * 16 + l16) * 64 + pc * 8]);
                    #pragma unroll
                    for (int mt = 0; mt < 2; ++mt)
                        #pragma unroll
                        for (int nt = 0; nt < 4; ++nt)
                            acc1[mt][nt] = __builtin_amdgcn_mfma_f32_16x16x32_bf16(
                                bf[nt], af[mt], acc1[mt][nt], 0, 0, 0);
                }
            }
            __syncthreads();
            {
                const float* bb1 = p.b1 + (long)z * 512 + c * 256;
                #pragma unroll
                for (int mt = 0; mt < 2; ++mt) {
                    int r = mt * 16 + l16;
                    #pragma unroll
                    for (int nt = 0; nt < 4; ++nt) {
                        int col = w * 64 + nt * 16 + q * 4;
                        float4 bv = *(const float4*)(bb1 + col);
                        f32x4 v = acc1[mt][nt];
                        u16x4 o;
                        o.x = f2bf(fmaxf(v.x + bv.x, 0.f));
                        o.y = f2bf(fmaxf(v.y + bv.y, 0.f));
                        o.z = f2bf(fmaxf(v.z + bv.z, 0.f));
                        o.w = f2bf(fmaxf(v.w + bv.w, 0.f));
                        int grp = col >> 3;
                        *(u16x4*)(&sH[r * 256 + ((grp ^ (r & 7)) << 3) + (q & 1) * 4]) = o;
                    }
                }
            }
            #pragma unroll
            for (int s = 0; s < 4; ++s) {
                __syncthreads();
                #pragma unroll
                for (int i = 0; i < 8; i++)
                    load_lds16(W2b + (long)(32 * i + tr) * 512 + c * 256 + s * 64 + lc * 8,
                               &sW[i * 2048 + ldst]);
                __syncthreads();
                #pragma unroll
                for (int kk = 0; kk < 2; ++kk) {
                    const int pc = ((kk << 2) | q) ^ key;
                    const int kg = s * 8 + ((kk << 2) | q);
                    s16x8 af[2], bf[4];
                    #pragma unroll
                    for (int mt = 0; mt < 2; ++mt) {
                        int r = mt * 16 + l16;
                        af[mt] = *(const s16x8*)(&sH[r * 256 + ((kg ^ key) << 3)]);
                    }
                    #pragma unroll
                    for (int nt = 0; nt < 4; ++nt)
                        bf[nt] = *(const s16x8*)(&sW[(w * 64 + nt * 16 + l16) * 64 + pc * 8]);
                    #pragma unroll
                    for (int mt = 0; mt < 2; ++mt)
                        #pragma unroll
                        for (int nt = 0; nt < 4; ++nt)
                            acc[mt][nt] = __builtin_amdgcn_mfma_f32_16x16x32_bf16(
                                bf[nt], af[mt], acc[mt][nt], 0, 0, 0);
                }
            }
        }
        #pragma unroll
        for (int mt = 0; mt < 2; ++mt) {
            int r = mt * 16 + l16;
            const float* g = sg[r];
            float c0 = (z == 0) ? g[0] : (z == 1) ? g[1] : (z == 4) ? g[2] : (z == 5) ? g[3] : 0.f;
            float c1 = (z == 2) ? g[4] : (z == 3) ? g[5] : (z == 4) ? g[6] : (z == 5) ? g[7] : 0.f;
            #pragma unroll
            for (int nt = 0; nt < 4; ++nt) {
                int gc = w * 64 + nt * 16 + q * 4;
                float4 bv = *(const float4*)(p.b2 + (long)z * 256 + gc);
                f32x4 v = acc[mt][nt];
                v.x = fmaxf(v.x + bv.x, 0.f);
                v.y = fmaxf(v.y + bv.y, 0.f);
                v.z = fmaxf(v.z + bv.z, 0.f);
                v.w = fmaxf(v.w + bv.w, 0.f);
                comb0[mt][nt] += v * c0;
                comb1[mt][nt] += v * c1;
            }
        }
    }

    #pragma unroll
    for (int mt = 0; mt < 2; ++mt) {
        long grow = m0 + mt * 16 + l16;
        #pragma unroll
        for (int nt = 0; nt < 4; ++nt) {
            int gc = w * 64 + nt * 16 + q * 4;
            u16x4 o;
            f32x4 v = comb0[mt][nt];
            o.x = f2bf(v.x); o.y = f2bf(v.y); o.z = f2bf(v.z); o.w = f2bf(v.w);
            *(u16x4*)(p.x2 + ((long)0 * BATCH + grow) * 256 + gc) = o;
            v = comb1[mt][nt];
            o.x = f2bf(v.x); o.y = f2bf(v.y); o.z = f2bf(v.z); o.w = f2bf(v.w);
            *(u16x4*)(p.x2 + ((long)1 * BATCH + grow) * 256 + gc) = o;
        }
    }
}

// ---------------------------------------------------------------------------
// Fused towers (unchanged)
// ---------------------------------------------------------------------------
__global__ __launch_bounds__(256, 1)
void tower_fused(const u16* __restrict__ x2, const u16* __restrict__ W1t,
                 const float* __restrict__ b1, const u16* __restrict__ W2t,
                 const float* __restrict__ b2, float* __restrict__ out) {
    const int t = blockIdx.y, m0 = blockIdx.x * 64;
    __shared__ u16 sX[64 * 256];
    __shared__ u16 sW1[128 * 256];
    __shared__ u16 sH[64 * 136];
    __shared__ u16 sW2[64 * 128];
    __shared__ float sB1[128];
    __shared__ float sB2[64];
    const int tid = threadIdx.x, lane = tid & 63, w = tid >> 6;
    const int l16 = lane & 15, q = lane >> 4;

    #pragma unroll
    for (int i = 0; i < 8; i++) {
        int c = i * 256 + tid, row = c >> 5, kc = c & 31;
        int lcc = (kc & ~7) | ((kc & 7) ^ (row & 7));
        load_lds16(x2 + ((long)t * BATCH + m0 + row) * 256 + lcc * 8,
                   &sX[(i * 256 + (tid & ~63)) * 8]);
    }
    #pragma unroll
    for (int i = 0; i < 16; i++) {
        int c = i * 256 + tid, row = c >> 5, kc = c & 31;
        int lcc = (kc & ~7) | ((kc & 7) ^ (row & 7));
        load_lds16(W1t + ((long)t * 128 + row) * 256 + lcc * 8,
                   &sW1[(i * 256 + (tid & ~63)) * 8]);
    }
    #pragma unroll
    for (int i = 0; i < 4; i++) {
        int c = i * 256 + tid, row = c >> 4, kc = c & 15;
        int lcc = (kc & ~7) | ((kc & 7) ^ (row & 7));
        load_lds16(W2t + ((long)t * 64 + row) * 128 + lcc * 8,
                   &sW2[(i * 256 + (tid & ~63)) * 8]);
    }
    if (tid < 128) sB1[tid] = b1[t * 128 + tid];
    if (tid < 64)  sB2[tid] = b2[t * 64 + tid];
    __syncthreads();

    f32x4 acc1[4][2] = {};
    #pragma unroll
    for (int kk = 0; kk < 8; kk++) {
        int pcb = kk * 4 + q;
        s16x8 af[4], bf[2];
        #pragma unroll
        for (int mt = 0; mt < 4; mt++) {
            int row = mt * 16 + l16;
            int sc = (pcb & ~7) | ((pcb & 7) ^ (row & 7));
            af[mt] = *(const s16x8*)(&sX[row * 256 + sc * 8]);
        }
        #pragma unroll
        for (int nt = 0; nt < 2; nt++) {
            int row = w * 32 + nt * 16 + l16;
            int sc = (pcb & ~7) | ((pcb & 7) ^ (row & 7));
            bf[nt] = *(const s16x8*)(&sW1[row * 256 + sc * 8]);
        }
        #pragma unroll
        for (int mt = 0; mt < 4; mt++)
            #pragma unroll
            for (int nt = 0; nt < 2; nt++)
                acc1[mt][nt] = __builtin_amdgcn_mfma_f32_16x16x32_bf16(
                    bf[nt], af[mt], acc1[mt][nt], 0, 0, 0);
    }
    #pragma unroll
    for (int mt = 0; mt < 4; mt++) {
        int row = mt * 16 + l16;
        #pragma unroll
        for (int nt = 0; nt < 2; nt++) {
            int col = w * 32 + nt * 16 + q * 4;
            f32x4 v = acc1[mt][nt];
            u16x4 o;
            o.x = f2bf(fmaxf(v.x + sB1[col + 0], 0.f));
            o.y = f2bf(fmaxf(v.y + sB1[col + 1], 0.f));
            o.z = f2bf(fmaxf(v.z + sB1[col + 2], 0.f));
            o.w = f2bf(fmaxf(v.w + sB1[col + 3], 0.f));
            *(u16x4*)(&sH[row * 136 + col]) = o;
        }
    }
    __syncthreads();

    f32x4 acc2[4] = {};
    #pragma unroll
    for (int kk = 0; kk < 4; kk++) {
        s16x8 af[4], bf;
        #pragma unroll
        for (int mt = 0; mt < 4; mt++) {
            int row = mt * 16 + l16;
            af[mt] = *(const s16x8*)(&sH[row * 136 + kk * 32 + q * 8]);
        }
        {
            int row = w * 16 + l16;
            int pc = kk * 4 + q;
            int sc = (pc & ~7) | ((pc & 7) ^ (row & 7));
            bf = *(const s16x8*)(&sW2[row * 128 + sc * 8]);
        }
        #pragma unroll
        for (int mt = 0; mt < 4; mt++)
            acc2[mt] = __builtin_amdgcn_mfma_f32_16x16x32_bf16(
                bf, af[mt], acc2[mt], 0, 0, 0);
    }
    #pragma unroll
    for (int mt = 0; mt < 4; mt++) {
        int grow = m0 + mt * 16 + l16;
        int col = w * 16 + q * 4;
        float4 bv = *(const float4*)(sB2 + col);
        f32x4 v = acc2[mt];
        float4 r;
        r.x = 1.f / (1.f + __expf(-(v.x + bv.x)));
        r.y = 1.f / (1.f + __expf(-(v.y + bv.y)));
        r.z = 1.f / (1.f + __expf(-(v.z + bv.z)));
        r.w = 1.f / (1.f + __expf(-(v.w + bv.w)));
        *(float4*)(out + (long)grow * 128 + t * 64 + col) = r;
    }
}

// ---------------------------------------------------------------------------
extern "C" void kernel_launch(void* const* d_in, const int* in_sizes, int n_in,
                              void* d_out, int out_size, void* d_ws, size_t ws_size,
                              hipStream_t stream) {
    const int*   x_ids = (const int*)  d_in[0];
    const float* emb   = (const float*)d_in[1];
    const float* e1W1  = (const float*)d_in[2];
    const float* e1b1  = (const float*)d_in[3];
    const float* e1W2  = (const float*)d_in[4];
    const float* e1b2  = (const float*)d_in[5];
    const float* g1Ws  = (const float*)d_in[6];
    const float* g1bs  = (const float*)d_in[7];
    const float* g1Wsh = (const float*)d_in[8];
    const float* g1bsh = (const float*)d_in[9];
    const float* e2W1  = (const float*)d_in[10];
    const float* e2b1  = (const float*)d_in[11];
    const float* e2W2  = (const float*)d_in[12];
    const float* e2b2  = (const float*)d_in[13];
    const float* g2Ws  = (const float*)d_in[14];
    const float* g2bs  = (const float*)d_in[15];
    const float* twW1  = (const float*)d_in[16];
    const float* twb1  = (const float*)d_in[17];
    const float* twW2  = (const float*)d_in[18];
    const float* twb2  = (const float*)d_in[19];
    float* out = (float*)d_out;

    char* ws = (char*)d_ws;
    u16* embed   = (u16*)(ws + 0);                       // [B,512]
    u16* wt_e1W1 = (u16*)(ws + 16777216);                // [6,512,512]
    u16* wt_e1W2 = (u16*)(ws + 19922944);                // [6,256,512]
    u16* wt_e2W1 = (u16*)(ws + 21495808);                // [6,512,256]
    u16* wt_e2W2 = (u16*)(ws + 23068672);                // [6,256,512]
    u16* wt_twW1 = (u16*)(ws + 24641536);                // [2,128,256]
    u16* wt_twW2 = (u16*)(ws + 24772608);                // [2,64,128]
    u16* x1      = (u16*)(ws + 175800320);               // [3,B,256]
    u16* x2      = (u16*)(ws + 200966144);               // [2,B,256]

    PrepArgs pa;
    pa.d[0] = { e1W1, wt_e1W1, 512, 512, 6,  0 };
    pa.d[1] = { e1W2, wt_e1W2, 512, 256, 6,  6 };
    pa.d[2] = { e2W1, wt_e2W1, 256, 512, 6, 12 };
    pa.d[3] = { e2W2, wt_e2W2, 512, 256, 6, 18 };
    pa.d[4] = { twW1, wt_twW1, 256, 128, 2, 24 };
    pa.d[5] = { twW2, wt_twW2, 128,  64, 2, 26 };
    prep_weights<<<dim3(16, 16, 28), 256, 0, stream>>>(pa);

    gather_embed<<<dim3(BATCH * NFEAT * 4 / 256), 256, 0, stream>>>(x_ids, emb, embed);

    MegaP1 m1 = { embed, wt_e1W1, wt_e1W2, e1b1, e1b2, g1Ws, g1bs, g1Wsh, g1bsh, x1 };
    mega_l1<<<dim3(BATCH / 32), 256, 0, stream>>>(m1);

    MegaP2 m2 = { x1, wt_e2W1, wt_e2W2, e2b1, e2b2, g2Ws, g2bs, x2 };
    mega_l2<<<dim3(BATCH / 32), 256, 0, stream>>>(m2);

    tower_fused<<<dim3(BATCH / 64, 2), 256, 0, stream>>>(x2, wt_twW1, twb1, wt_twW2, twb2, out);
}

// Round 8
// 526.726 us; speedup vs baseline: 1.0680x; 1.0029x over previous
//
#include <hip/hip_runtime.h>

typedef unsigned short u16;
typedef __attribute__((ext_vector_type(4))) unsigned short u16x4;
typedef __attribute__((ext_vector_type(8))) unsigned short u16x8;
typedef __attribute__((ext_vector_type(8))) short s16x8;
typedef __attribute__((ext_vector_type(4))) float f32x4;

#define BATCH 16384
#define NFEAT 32
#define NVOCAB 50000

__device__ __forceinline__ u16 f2bf(float f) {
    union { float f; unsigned u; } v; v.f = f;
    unsigned u = v.u;
    return (u16)((u + 0x7fffu + ((u >> 16) & 1u)) >> 16);
}
__device__ __forceinline__ float bf2f(u16 h) {
    union { unsigned u; float f; } v; v.u = ((unsigned)h) << 16;
    return v.f;
}

__device__ __forceinline__ void load_lds16(const u16* g, u16* l) {
    __builtin_amdgcn_global_load_lds(
        (const __attribute__((address_space(1))) void*)g,
        (__attribute__((address_space(3))) void*)l, 16, 0, 0);
}

// ---------------------------------------------------------------------------
// Weight prep: fp32 [z][K][N] -> bf16 [z][N][K] (transposed, K-contiguous)
// ---------------------------------------------------------------------------
struct PrepDesc { const float* src; u16* dst; int K; int N; int nz; int zbase; };
struct PrepArgs { PrepDesc d[6]; };

__global__ void prep_weights(PrepArgs args) {
    int z = blockIdx.z;
    int di = 0;
    #pragma unroll
    for (int i = 0; i < 6; i++)
        if (z >= args.d[i].zbase && z < args.d[i].zbase + args.d[i].nz) di = i;
    PrepDesc d = args.d[di];
    int zz = z - d.zbase;
    int k0 = blockIdx.x * 32, n0 = blockIdx.y * 32;
    if (k0 >= d.K || n0 >= d.N) return;
    __shared__ float tile[32][33];
    const float* src = d.src + (long)zz * d.K * d.N;
    u16* dst = d.dst + (long)zz * d.K * d.N;
    int tx = threadIdx.x & 31, ty = threadIdx.x >> 5;
    for (int r = ty; r < 32; r += 8) {
        int k = k0 + r, n = n0 + tx;
        tile[r][tx] = (k < d.K && n < d.N) ? src[(long)k * d.N + n] : 0.f;
    }
    __syncthreads();
    for (int r = ty; r < 32; r += 8) {
        int n = n0 + r, k = k0 + tx;
        if (n < d.N && k < d.K) dst[(long)n * d.K + k] = f2bf(tile[tx][r]);
    }
}

// ---------------------------------------------------------------------------
// Embedding gather
// ---------------------------------------------------------------------------
__global__ void gather_embed(const int* __restrict__ ids,
                             const float* __restrict__ emb,
                             u16* __restrict__ out) {
    int idx = blockIdx.x * 256 + threadIdx.x;
    int d4 = idx & 3;
    int f  = (idx >> 2) & 31;
    int b  = idx >> 7;
    int id = ids[b * NFEAT + f];
    const float4* p = (const float4*)(emb + ((long)f * NVOCAB + id) * 16) + d4;
    float4 v = *p;
    u16x4 o;
    o.x = f2bf(v.x); o.y = f2bf(v.y); o.z = f2bf(v.z); o.w = f2bf(v.w);
    *(u16x4*)(out + (long)b * 512 + f * 16 + d4 * 4) = o;
}

// ---------------------------------------------------------------------------
// Fused two-layer expert, 128-row blocks (R4 structure scaled up):
//   O[z] = relu(relu(A[zsel] @ W1[z] + b1) @ W2[z] + b2)
// 512 threads = 8 waves (2M x 4N). Per chunk (128 H-cols):
//   stage1: per k-tile stage sA(16KB)+sW1(16KB) -> 16 MFMA/wave;
//   H epilogue -> swizzled sH (128x128, 32KB, ALIASED with sA — never
//   simultaneously live; the sync before the H-write makes it safe);
//   stage2: 2 x { stage sW2(32KB) -> 16 MFMA/wave } into persistent acc.
// Staged bytes/FLOP: 15 KB/MF stage1, 7.6 KB/MF stage2 (vs 23 at 64 rows).
// LDS = 64KB -> 2 blocks/CU, 16 waves/CU.
// ---------------------------------------------------------------------------
struct FusedP {
    const u16* A; const u16* W1t; const float* b1;
    const u16* W2t; const float* b2; u16* O;
    int a_zshift; long a_zstride;
};

template<int NKT>   // K1/64: 8 for level-1 (K=512), 4 for level-2 (K=256)
__device__ __forceinline__ void expert_impl(const FusedP p) {
    __shared__ u16 smem[32768];       // 64KB: [0,16384)=sH(32KB)/sA(16KB alias), [16384,..)=sW(32KB)
    u16* sA = smem;
    u16* sH = smem;
    u16* sW = smem + 16384;
    const int K1 = NKT * 64;
    const int z = blockIdx.z;
    const int m0 = blockIdx.x * 128;
    const u16* Ab  = p.A + (long)(z >> p.a_zshift) * p.a_zstride;
    const u16* W1b = p.W1t + (long)z * 512 * K1;   // [512 H-cols][K1]
    const u16* W2b = p.W2t + (long)z * 256 * 512;  // [256 out-cols][512]
    const int tid = threadIdx.x;
    const int lane = tid & 63;
    const int w = tid >> 6;           // 8 waves
    const int wm = w >> 2;            // 2 M-halves (64 rows each)
    const int wn = w & 3;             // 4 N-quarters
    const int l16 = lane & 15;
    const int q = lane >> 4;
    const int key = l16 & 7;

    // staging: tr = row 0..63 per 64-row round, source col pre-swizzled
    const int tr = tid >> 3;
    const int lc = (tid & 7) ^ (tr & 7);
    const u16* gA0 = Ab + (long)(m0 + tr) * K1 + lc * 8;
    const int ldst = (tid & ~63) * 8; // wave-uniform LDS base (elems), 8KB/load w/ 512 thr

    f32x4 acc[4][4] = {};             // O acc: rows wm*64+mt*16+l16, cols wn*64+nt*16+q*4

    #pragma unroll
    for (int c = 0; c < 4; ++c) {
        f32x4 acc1[4][2] = {};        // H acc: rows wm*64+mt*16+l16, cols wn*32+nt*16+q*4
        // ---- stage 1: H_c = A @ W1[:, c*128..+127] ----
        for (int kt = 0; kt < NKT; ++kt) {
            __syncthreads();          // prev readers of sA/sH-alias and sW done
            load_lds16(gA0 + kt * 64,                  &sA[ldst]);          // rows 0..63
            load_lds16(gA0 + (long)64 * K1 + kt * 64,  &sA[4096 + ldst]);   // rows 64..127
            #pragma unroll
            for (int i = 0; i < 2; ++i)
                load_lds16(W1b + (long)(c * 128 + 64 * i + tr) * K1 + kt * 64 + lc * 8,
                           &sW[i * 4096 + ldst]);
            __syncthreads();
            #pragma unroll
            for (int kk = 0; kk < 2; ++kk) {
                const int pc = ((kk << 2) | q) ^ key;
                s16x8 af[4], bf[2];
                #pragma unroll
                for (int mt = 0; mt < 4; ++mt)
                    af[mt] = *(const s16x8*)(&sA[(wm * 64 + mt * 16 + l16) * 64 + pc * 8]);
                #pragma unroll
                for (int nt = 0; nt < 2; ++nt)
                    bf[nt] = *(const s16x8*)(&sW[(wn * 32 + nt * 16 + l16) * 64 + pc * 8]);
                #pragma unroll
                for (int mt = 0; mt < 4; ++mt)
                    #pragma unroll
                    for (int nt = 0; nt < 2; ++nt)
                        acc1[mt][nt] = __builtin_amdgcn_mfma_f32_16x16x32_bf16(
                            bf[nt], af[mt], acc1[mt][nt], 0, 0, 0);
            }
        }
        __syncthreads();              // ALL waves' sA reads done -> safe to write sH alias
        // ---- H epilogue: bias + relu + bf16 -> swizzled sH (128x128) ----
        {
            const float* bb1 = p.b1 + (long)z * 512 + c * 128;
            #pragma unroll
            for (int mt = 0; mt < 4; ++mt) {
                int r = wm * 64 + mt * 16 + l16;
                #pragma unroll
                for (int nt = 0; nt < 2; ++nt) {
                    int col = wn * 32 + nt * 16 + q * 4;
                    float4 bv = *(const float4*)(bb1 + col);
                    f32x4 v = acc1[mt][nt];
                    u16x4 o;
                    o.x = f2bf(fmaxf(v.x + bv.x, 0.f));
                    o.y = f2bf(fmaxf(v.y + bv.y, 0.f));
                    o.z = f2bf(fmaxf(v.z + bv.z, 0.f));
                    o.w = f2bf(fmaxf(v.w + bv.w, 0.f));
                    int grp = col >> 3;            // 16B group (0..15)
                    *(u16x4*)(&sH[r * 128 + ((grp ^ (r & 7)) << 3) + (q & 1) * 4]) = o;
                }
            }
        }
        // ---- stage 2: acc += H_c @ W2[c*128.., :] ----
        #pragma unroll
        for (int s = 0; s < 2; ++s) {
            __syncthreads();          // orders sH writes (s=0) / protects sW readers (s=1)
            #pragma unroll
            for (int i = 0; i < 4; ++i)
                load_lds16(W2b + (long)(64 * i + tr) * 512 + c * 128 + s * 64 + lc * 8,
                           &sW[i * 4096 + ldst]);
            __syncthreads();
            #pragma unroll
            for (int kk = 0; kk < 2; ++kk) {
                const int kg = s * 8 + ((kk << 2) | q);   // sH k-group (pre-swizzle)
                const int pc = ((kk << 2) | q) ^ key;     // sW local group
                s16x8 af[4], bf[4];
                #pragma unroll
                for (int mt = 0; mt < 4; ++mt) {
                    int r = wm * 64 + mt * 16 + l16;
                    af[mt] = *(const s16x8*)(&sH[r * 128 + ((kg ^ key) << 3)]);
                }
                #pragma unroll
                for (int nt = 0; nt < 4; ++nt)
                    bf[nt] = *(const s16x8*)(&sW[(wn * 64 + nt * 16 + l16) * 64 + pc * 8]);
                #pragma unroll
                for (int mt = 0; mt < 4; ++mt)
                    #pragma unroll
                    for (int nt = 0; nt < 4; ++nt)
                        acc[mt][nt] = __builtin_amdgcn_mfma_f32_16x16x32_bf16(
                            bf[nt], af[mt], acc[mt][nt], 0, 0, 0);
            }
        }
    }

    // ---- O epilogue ----
    const float* bb2 = p.b2 + (long)z * 256;
    u16* Op = p.O + (long)z * BATCH * 256;
    #pragma unroll
    for (int mt = 0; mt < 4; ++mt) {
        int grow = m0 + wm * 64 + mt * 16 + l16;
        u16* rowp = Op + (long)grow * 256;
        #pragma unroll
        for (int nt = 0; nt < 4; ++nt) {
            int gc = wn * 64 + nt * 16 + q * 4;
            float4 bv = *(const float4*)(bb2 + gc);
            f32x4 v = acc[mt][nt];
            v.x = fmaxf(v.x + bv.x, 0.f);
            v.y = fmaxf(v.y + bv.y, 0.f);
            v.z = fmaxf(v.z + bv.z, 0.f);
            v.w = fmaxf(v.w + bv.w, 0.f);
            u16x4 o;
            o.x = f2bf(v.x); o.y = f2bf(v.y); o.z = f2bf(v.z); o.w = f2bf(v.w);
            *(u16x4*)(rowp + gc) = o;
        }
    }
}

__global__ __launch_bounds__(512, 2) void fused_l1(FusedP p) { expert_impl<8>(p); }
__global__ __launch_bounds__(512, 2) void fused_l2(FusedP p) { expert_impl<4>(p); }

// ---------------------------------------------------------------------------
// Fused towers (unchanged)
// ---------------------------------------------------------------------------
__global__ __launch_bounds__(256, 1)
void tower_fused(const u16* __restrict__ x2, const u16* __restrict__ W1t,
                 const float* __restrict__ b1, const u16* __restrict__ W2t,
                 const float* __restrict__ b2, float* __restrict__ out) {
    const int t = blockIdx.y, m0 = blockIdx.x * 64;
    __shared__ u16 sX[64 * 256];
    __shared__ u16 sW1[128 * 256];
    __shared__ u16 sH[64 * 136];
    __shared__ u16 sW2[64 * 128];
    __shared__ float sB1[128];
    __shared__ float sB2[64];
    const int tid = threadIdx.x, lane = tid & 63, w = tid >> 6;
    const int l16 = lane & 15, q = lane >> 4;

    #pragma unroll
    for (int i = 0; i < 8; i++) {
        int c = i * 256 + tid, row = c >> 5, kc = c & 31;
        int lcc = (kc & ~7) | ((kc & 7) ^ (row & 7));
        load_lds16(x2 + ((long)t * BATCH + m0 + row) * 256 + lcc * 8,
                   &sX[(i * 256 + (tid & ~63)) * 8]);
    }
    #pragma unroll
    for (int i = 0; i < 16; i++) {
        int c = i * 256 + tid, row = c >> 5, kc = c & 31;
        int lcc = (kc & ~7) | ((kc & 7) ^ (row & 7));
        load_lds16(W1t + ((long)t * 128 + row) * 256 + lcc * 8,
                   &sW1[(i * 256 + (tid & ~63)) * 8]);
    }
    #pragma unroll
    for (int i = 0; i < 4; i++) {
        int c = i * 256 + tid, row = c >> 4, kc = c & 15;
        int lcc = (kc & ~7) | ((kc & 7) ^ (row & 7));
        load_lds16(W2t + ((long)t * 64 + row) * 128 + lcc * 8,
                   &sW2[(i * 256 + (tid & ~63)) * 8]);
    }
    if (tid < 128) sB1[tid] = b1[t * 128 + tid];
    if (tid < 64)  sB2[tid] = b2[t * 64 + tid];
    __syncthreads();

    f32x4 acc1[4][2] = {};
    #pragma unroll
    for (int kk = 0; kk < 8; kk++) {
        int pcb = kk * 4 + q;
        s16x8 af[4], bf[2];
        #pragma unroll
        for (int mt = 0; mt < 4; mt++) {
            int row = mt * 16 + l16;
            int sc = (pcb & ~7) | ((pcb & 7) ^ (row & 7));
            af[mt] = *(const s16x8*)(&sX[row * 256 + sc * 8]);
        }
        #pragma unroll
        for (int nt = 0; nt < 2; nt++) {
            int row = w * 32 + nt * 16 + l16;
            int sc = (pcb & ~7) | ((pcb & 7) ^ (row & 7));
            bf[nt] = *(const s16x8*)(&sW1[row * 256 + sc * 8]);
        }
        #pragma unroll
        for (int mt = 0; mt < 4; mt++)
            #pragma unroll
            for (int nt = 0; nt < 2; nt++)
                acc1[mt][nt] = __builtin_amdgcn_mfma_f32_16x16x32_bf16(
                    bf[nt], af[mt], acc1[mt][nt], 0, 0, 0);
    }
    #pragma unroll
    for (int mt = 0; mt < 4; mt++) {
        int row = mt * 16 + l16;
        #pragma unroll
        for (int nt = 0; nt < 2; nt++) {
            int col = w * 32 + nt * 16 + q * 4;
            f32x4 v = acc1[mt][nt];
            u16x4 o;
            o.x = f2bf(fmaxf(v.x + sB1[col + 0], 0.f));
            o.y = f2bf(fmaxf(v.y + sB1[col + 1], 0.f));
            o.z = f2bf(fmaxf(v.z + sB1[col + 2], 0.f));
            o.w = f2bf(fmaxf(v.w + sB1[col + 3], 0.f));
            *(u16x4*)(&sH[row * 136 + col]) = o;
        }
    }
    __syncthreads();

    f32x4 acc2[4] = {};
    #pragma unroll
    for (int kk = 0; kk < 4; kk++) {
        s16x8 af[4], bf;
        #pragma unroll
        for (int mt = 0; mt < 4; mt++) {
            int row = mt * 16 + l16;
            af[mt] = *(const s16x8*)(&sH[row * 136 + kk * 32 + q * 8]);
        }
        {
            int row = w * 16 + l16;
            int pc = kk * 4 + q;
            int sc = (pc & ~7) | ((pc & 7) ^ (row & 7));
            bf = *(const s16x8*)(&sW2[row * 128 + sc * 8]);
        }
        #pragma unroll
        for (int mt = 0; mt < 4; mt++)
            acc2[mt] = __builtin_amdgcn_mfma_f32_16x16x32_bf16(
                bf, af[mt], acc2[mt], 0, 0, 0);
    }
    #pragma unroll
    for (int mt = 0; mt < 4; mt++) {
        int grow = m0 + mt * 16 + l16;
        int col = w * 16 + q * 4;
        float4 bv = *(const float4*)(sB2 + col);
        f32x4 v = acc2[mt];
        float4 r;
        r.x = 1.f / (1.f + __expf(-(v.x + bv.x)));
        r.y = 1.f / (1.f + __expf(-(v.y + bv.y)));
        r.z = 1.f / (1.f + __expf(-(v.z + bv.z)));
        r.w = 1.f / (1.f + __expf(-(v.w + bv.w)));
        *(float4*)(out + (long)grow * 128 + t * 64 + col) = r;
    }
}

// ---------------------------------------------------------------------------
// Level-1 fused gates+combine (unchanged)
// ---------------------------------------------------------------------------
__global__ __launch_bounds__(256)
void gate1(const u16* __restrict__ embed, const u16* __restrict__ out1,
           const float* __restrict__ g1Ws, const float* __restrict__ g1bs,
           const float* __restrict__ gWsh, const float* __restrict__ gbsh,
           u16* __restrict__ x1) {
    const int m0 = blockIdx.x * 8;
    __shared__ float sg[8][16];
    const int tid = threadIdx.x;
    const int row = tid >> 5, l = tid & 31;
    const long rb = m0 + row;

    float a[4] = {0,0,0,0}, b[4] = {0,0,0,0}, c[6] = {0,0,0,0,0,0};
    {
        const u16* er = embed + rb * 512 + l * 16;
        u16x8 xa = *(const u16x8*)(er);
        u16x8 xb = *(const u16x8*)(er + 8);
        #pragma unroll
        for (int u = 0; u < 16; u++) {
            int k = l * 16 + u;
            float xv = bf2f(u < 8 ? xa[u] : xb[u - 8]);
            float4 wa = *(const float4*)(g1Ws + k * 4);
            float4 wb = *(const float4*)(g1Ws + 2048 + k * 4);
            a[0] += xv * wa.x; a[1] += xv * wa.y; a[2] += xv * wa.z; a[3] += xv * wa.w;
            b[0] += xv * wb.x; b[1] += xv * wb.y; b[2] += xv * wb.z; b[3] += xv * wb.w;
            float2 w0 = *(const float2*)(gWsh + k * 6);
            float2 w1 = *(const float2*)(gWsh + k * 6 + 2);
            float2 w2 = *(const float2*)(gWsh + k * 6 + 4);
            c[0] += xv * w0.x; c[1] += xv * w0.y;
            c[2] += xv * w1.x; c[3] += xv * w1.y;
            c[4] += xv * w2.x; c[5] += xv * w2.y;
        }
    }
    #pragma unroll
    for (int off = 1; off < 32; off <<= 1) {
        #pragma unroll
        for (int g = 0; g < 4; g++) { a[g] += __shfl_xor(a[g], off); b[g] += __shfl_xor(b[g], off); }
        #pragma unroll
        for (int g = 0; g < 6; g++) c[g] += __shfl_xor(c[g], off);
    }
    if (l == 0) {
        float mx, s, e[6];
        mx = -1e30f;
        for (int g = 0; g < 4; g++) { a[g] += g1bs[g]; mx = fmaxf(mx, a[g]); }
        s = 0.f; for (int g = 0; g < 4; g++) { e[g] = __expf(a[g] - mx); s += e[g]; }
        for (int g = 0; g < 4; g++) sg[row][g] = e[g] / s;
        mx = -1e30f;
        for (int g = 0; g < 4; g++) { b[g] += g1bs[4 + g]; mx = fmaxf(mx, b[g]); }
        s = 0.f; for (int g = 0; g < 4; g++) { e[g] = __expf(b[g] - mx); s += e[g]; }
        for (int g = 0; g < 4; g++) sg[row][4 + g] = e[g] / s;
        mx = -1e30f;
        for (int g = 0; g < 6; g++) { c[g] += gbsh[g]; mx = fmaxf(mx, c[g]); }
        s = 0.f; for (int g = 0; g < 6; g++) { e[g] = __expf(c[g] - mx); s += e[g]; }
        for (int g = 0; g < 6; g++) sg[row][8 + g] = e[g] / s;
    }
    __syncthreads();

    const int c8 = l * 8;
    const u16* ob = out1 + rb * 256 + c8;
    u16x8 o[6];
    #pragma unroll
    for (int k = 0; k < 6; k++) o[k] = *(const u16x8*)(ob + (long)k * BATCH * 256);
    const float* g = sg[row];
    u16x8 r0, r1, r2;
    #pragma unroll
    for (int u = 0; u < 8; u++) {
        float o0 = bf2f(o[0][u]), o1 = bf2f(o[1][u]), o2 = bf2f(o[2][u]);
        float o3 = bf2f(o[3][u]), o4 = bf2f(o[4][u]), o5 = bf2f(o[5][u]);
        r0[u] = f2bf(g[0] * o0 + g[1] * o1 + g[2] * o4 + g[3] * o5);
        r1[u] = f2bf(g[4] * o2 + g[5] * o3 + g[6] * o4 + g[7] * o5);
        r2[u] = f2bf(g[8] * o0 + g[9] * o1 + g[10] * o2 + g[11] * o3 + g[12] * o4 + g[13] * o5);
    }
    *(u16x8*)(x1 + ((long)0 * BATCH + rb) * 256 + c8) = r0;
    *(u16x8*)(x1 + ((long)1 * BATCH + rb) * 256 + c8) = r1;
    *(u16x8*)(x1 + ((long)2 * BATCH + rb) * 256 + c8) = r2;
}

// ---------------------------------------------------------------------------
// Level-2 fused gates+combine (unchanged)
// ---------------------------------------------------------------------------
__global__ __launch_bounds__(256)
void gate2(const u16* __restrict__ x1, const u16* __restrict__ out2,
           const float* __restrict__ g2Ws, const float* __restrict__ g2bs,
           u16* __restrict__ x2) {
    const int m0 = blockIdx.x * 8;
    __shared__ float sg[8][8];
    const int tid = threadIdx.x;
    const int row = tid >> 5, l = tid & 31;
    const long rb = m0 + row;

    float a[4] = {0,0,0,0}, b[4] = {0,0,0,0};
    {
        const u16* e0 = x1 + rb * 256 + l * 8;
        const u16* e1 = e0 + (long)BATCH * 256;
        u16x8 x0 = *(const u16x8*)e0;
        u16x8 x1v = *(const u16x8*)e1;
        #pragma unroll
        for (int u = 0; u < 8; u++) {
            int k = l * 8 + u;
            float4 wa = *(const float4*)(g2Ws + k * 4);
            float4 wb = *(const float4*)(g2Ws + 1024 + k * 4);
            float xv0 = bf2f(x0[u]), xv1 = bf2f(x1v[u]);
            a[0] += xv0 * wa.x; a[1] += xv0 * wa.y; a[2] += xv0 * wa.z; a[3] += xv0 * wa.w;
            b[0] += xv1 * wb.x; b[1] += xv1 * wb.y; b[2] += xv1 * wb.z; b[3] += xv1 * wb.w;
        }
    }
    #pragma unroll
    for (int off = 1; off < 32; off <<= 1) {
        #pragma unroll
        for (int g = 0; g < 4; g++) { a[g] += __shfl_xor(a[g], off); b[g] += __shfl_xor(b[g], off); }
    }
    if (l == 0) {
        float mx, s, e[4];
        mx = -1e30f;
        for (int g = 0; g < 4; g++) { a[g] += g2bs[g]; mx = fmaxf(mx, a[g]); }
        s = 0.f; for (int g = 0; g < 4; g++) { e[g] = __expf(a[g] - mx); s += e[g]; }
        for (int g = 0; g < 4; g++) sg[row][g] = e[g] / s;
        mx = -1e30f;
        for (int g = 0; g < 4; g++) { b[g] += g2bs[4 + g]; mx = fmaxf(mx, b[g]); }
        s = 0.f; for (int g = 0; g < 4; g++) { e[g] = __expf(b[g] - mx); s += e[g]; }
        for (int g = 0; g < 4; g++) sg[row][4 + g] = e[g] / s;
    }
    __syncthreads();

    const int c8 = l * 8;
    const u16* ob = out2 + rb * 256 + c8;
    u16x8 o[6];
    #pragma unroll
    for (int k = 0; k < 6; k++) o[k] = *(const u16x8*)(ob + (long)k * BATCH * 256);
    const float* g = sg[row];
    u16x8 r0, r1;
    #pragma unroll
    for (int u = 0; u < 8; u++) {
        float o0 = bf2f(o[0][u]), o1 = bf2f(o[1][u]), o2 = bf2f(o[2][u]);
        float o3 = bf2f(o[3][u]), o4 = bf2f(o[4][u]), o5 = bf2f(o[5][u]);
        r0[u] = f2bf(g[0] * o0 + g[1] * o1 + g[2] * o4 + g[3] * o5);
        r1[u] = f2bf(g[4] * o2 + g[5] * o3 + g[6] * o4 + g[7] * o5);
    }
    *(u16x8*)(x2 + ((long)0 * BATCH + rb) * 256 + c8) = r0;
    *(u16x8*)(x2 + ((long)1 * BATCH + rb) * 256 + c8) = r1;
}

// ---------------------------------------------------------------------------
extern "C" void kernel_launch(void* const* d_in, const int* in_sizes, int n_in,
                              void* d_out, int out_size, void* d_ws, size_t ws_size,
                              hipStream_t stream) {
    const int*   x_ids = (const int*)  d_in[0];
    const float* emb   = (const float*)d_in[1];
    const float* e1W1  = (const float*)d_in[2];
    const float* e1b1  = (const float*)d_in[3];
    const float* e1W2  = (const float*)d_in[4];
    const float* e1b2  = (const float*)d_in[5];
    const float* g1Ws  = (const float*)d_in[6];
    const float* g1bs  = (const float*)d_in[7];
    const float* g1Wsh = (const float*)d_in[8];
    const float* g1bsh = (const float*)d_in[9];
    const float* e2W1  = (const float*)d_in[10];
    const float* e2b1  = (const float*)d_in[11];
    const float* e2W2  = (const float*)d_in[12];
    const float* e2b2  = (const float*)d_in[13];
    const float* g2Ws  = (const float*)d_in[14];
    const float* g2bs  = (const float*)d_in[15];
    const float* twW1  = (const float*)d_in[16];
    const float* twb1  = (const float*)d_in[17];
    const float* twW2  = (const float*)d_in[18];
    const float* twb2  = (const float*)d_in[19];
    float* out = (float*)d_out;

    char* ws = (char*)d_ws;
    u16* embed   = (u16*)(ws + 0);                       // [B,512]
    u16* wt_e1W1 = (u16*)(ws + 16777216);                // [6,512,512]
    u16* wt_e1W2 = (u16*)(ws + 19922944);                // [6,256,512]
    u16* wt_e2W1 = (u16*)(ws + 21495808);                // [6,512,256]
    u16* wt_e2W2 = (u16*)(ws + 23068672);                // [6,256,512]
    u16* wt_twW1 = (u16*)(ws + 24641536);                // [2,128,256]
    u16* wt_twW2 = (u16*)(ws + 24772608);                // [2,64,128]
    u16* o_buf   = (u16*)(ws + 125468672);               // [6,B,256]
    u16* x1      = (u16*)(ws + 175800320);               // [3,B,256]
    u16* x2      = (u16*)(ws + 200966144);               // [2,B,256]

    PrepArgs pa;
    pa.d[0] = { e1W1, wt_e1W1, 512, 512, 6,  0 };
    pa.d[1] = { e1W2, wt_e1W2, 512, 256, 6,  6 };
    pa.d[2] = { e2W1, wt_e2W1, 256, 512, 6, 12 };
    pa.d[3] = { e2W2, wt_e2W2, 512, 256, 6, 18 };
    pa.d[4] = { twW1, wt_twW1, 256, 128, 2, 24 };
    pa.d[5] = { twW2, wt_twW2, 128,  64, 2, 26 };
    prep_weights<<<dim3(16, 16, 28), 256, 0, stream>>>(pa);

    gather_embed<<<dim3(BATCH * NFEAT * 4 / 256), 256, 0, stream>>>(x_ids, emb, embed);

    // Level 1: fused two-layer experts, 128-row blocks
    FusedP f1 = { embed, wt_e1W1, e1b1, wt_e1W2, e1b2, o_buf, 3, 0L };
    fused_l1<<<dim3(BATCH / 128, 1, 6), 512, 0, stream>>>(f1);

    gate1<<<dim3(BATCH / 8), 256, 0, stream>>>(embed, o_buf, g1Ws, g1bs, g1Wsh, g1bsh, x1);

    // Level 2
    FusedP f2 = { x1, wt_e2W1, e2b1, wt_e2W2, e2b2, o_buf, 1, (long)BATCH * 256 };
    fused_l2<<<dim3(BATCH / 128, 1, 6), 512, 0, stream>>>(f2);

    gate2<<<dim3(BATCH / 8), 256, 0, stream>>>(x1, o_buf, g2Ws, g2bs, x2);

    tower_fused<<<dim3(BATCH / 64, 2), 256, 0, stream>>>(x2, wt_twW1, twb1, wt_twW2, twb2, out);
}

// Round 9
// 467.684 us; speedup vs baseline: 1.2028x; 1.1262x over previous
//
#include <hip/hip_runtime.h>

typedef unsigned short u16;
typedef __attribute__((ext_vector_type(4))) unsigned short u16x4;
typedef __attribute__((ext_vector_type(8))) unsigned short u16x8;
typedef __attribute__((ext_vector_type(8))) short s16x8;
typedef __attribute__((ext_vector_type(4))) float f32x4;

#define BATCH 16384
#define NFEAT 32
#define NVOCAB 50000

__device__ __forceinline__ u16 f2bf(float f) {
    union { float f; unsigned u; } v; v.f = f;
    unsigned u = v.u;
    return (u16)((u + 0x7fffu + ((u >> 16) & 1u)) >> 16);
}
__device__ __forceinline__ float bf2f(u16 h) {
    union { unsigned u; float f; } v; v.u = ((unsigned)h) << 16;
    return v.f;
}

__device__ __forceinline__ void load_lds16(const u16* g, u16* l) {
    __builtin_amdgcn_global_load_lds(
        (const __attribute__((address_space(1))) void*)g,
        (__attribute__((address_space(3))) void*)l, 16, 0, 0);
}

// ---------------------------------------------------------------------------
// Weight prep: fp32 [z][K][N] -> bf16 [z][N][K] (transposed, K-contiguous)
// ---------------------------------------------------------------------------
struct PrepDesc { const float* src; u16* dst; int K; int N; int nz; int zbase; };
struct PrepArgs { PrepDesc d[6]; };

__global__ void prep_weights(PrepArgs args) {
    int z = blockIdx.z;
    int di = 0;
    #pragma unroll
    for (int i = 0; i < 6; i++)
        if (z >= args.d[i].zbase && z < args.d[i].zbase + args.d[i].nz) di = i;
    PrepDesc d = args.d[di];
    int zz = z - d.zbase;
    int k0 = blockIdx.x * 32, n0 = blockIdx.y * 32;
    if (k0 >= d.K || n0 >= d.N) return;
    __shared__ float tile[32][33];
    const float* src = d.src + (long)zz * d.K * d.N;
    u16* dst = d.dst + (long)zz * d.K * d.N;
    int tx = threadIdx.x & 31, ty = threadIdx.x >> 5;
    for (int r = ty; r < 32; r += 8) {
        int k = k0 + r, n = n0 + tx;
        tile[r][tx] = (k < d.K && n < d.N) ? src[(long)k * d.N + n] : 0.f;
    }
    __syncthreads();
    for (int r = ty; r < 32; r += 8) {
        int n = n0 + r, k = k0 + tx;
        if (n < d.N && k < d.K) dst[(long)n * d.K + k] = f2bf(tile[tx][r]);
    }
}

// ---------------------------------------------------------------------------
// Embedding gather
// ---------------------------------------------------------------------------
__global__ void gather_embed(const int* __restrict__ ids,
                             const float* __restrict__ emb,
                             u16* __restrict__ out) {
    int idx = blockIdx.x * 256 + threadIdx.x;
    int d4 = idx & 3;
    int f  = (idx >> 2) & 31;
    int b  = idx >> 7;
    int id = ids[b * NFEAT + f];
    const float4* p = (const float4*)(emb + ((long)f * NVOCAB + id) * 16) + d4;
    float4 v = *p;
    u16x4 o;
    o.x = f2bf(v.x); o.y = f2bf(v.y); o.z = f2bf(v.z); o.w = f2bf(v.w);
    *(u16x4*)(out + (long)b * 512 + f * 16 + d4 * 4) = o;
}

// ---------------------------------------------------------------------------
// Fused two-layer expert (R4 structure, best measured: 140/120 us):
//   O[z] = relu(relu(A[zsel] @ W1[z] + b1) @ W2[z] + b2)
// Per block: 64 rows x full expert. H (64x512) never leaves the CU.
// ---------------------------------------------------------------------------
struct FusedP {
    const u16* A; const u16* W1t; const float* b1;
    const u16* W2t; const float* b2; u16* O;
    int K1, a_zshift; long a_zstride;
};

__device__ __forceinline__ void expert_impl(const FusedP p) {
    __shared__ u16 sA[64 * 64];       // 8KB  A-tile (64 rows x 64 k)
    __shared__ u16 sW[256 * 64];      // 32KB W1-tile (128x64) / W2-tile (256x64)
    __shared__ u16 sH[64 * 128];      // 16KB H chunk, XOR-swizzled
    const int z = blockIdx.z;
    const int m0 = blockIdx.x * 64;
    const u16* Ab  = p.A + (long)(z >> p.a_zshift) * p.a_zstride;
    const u16* W1b = p.W1t + (long)z * 512 * p.K1;
    const u16* W2b = p.W2t + (long)z * 256 * 512;
    const int K1 = p.K1;
    const int tid = threadIdx.x;
    const int lane = tid & 63;
    const int w = tid >> 6;           // 4 waves
    const int l16 = lane & 15;
    const int q = lane >> 4;
    const int key = l16 & 7;

    const int tr = tid >> 3;
    const int lc = (tid & 7) ^ (tr & 7);
    const u16* gA0 = Ab + (long)(m0 + tr) * K1 + lc * 8;
    const int ldst = (tid & ~63) * 8;

    f32x4 acc[4][4] = {};             // persistent O acc

    #pragma unroll
    for (int c = 0; c < 4; c++) {
        f32x4 acc1[4][2] = {};        // H chunk acc
        // ---- stage 1: H_c = A @ W1[:, c*128 .. c*128+127] ----
        for (int k0 = 0; k0 < K1; k0 += 64) {
            __syncthreads();
            #pragma unroll
            for (int i = 0; i < 2; i++)
                load_lds16(gA0 + (long)(32 * i) * K1 + k0, &sA[i * 2048 + ldst]);
            #pragma unroll
            for (int i = 0; i < 4; i++)
                load_lds16(W1b + (long)(c * 128 + 32 * i + tr) * K1 + k0 + lc * 8,
                           &sW[i * 2048 + ldst]);
            __syncthreads();
            #pragma unroll
            for (int kk = 0; kk < 2; kk++) {
                const int pc = ((kk << 2) | q) ^ key;
                s16x8 af[4], bf[2];
                #pragma unroll
                for (int mt = 0; mt < 4; mt++)
                    af[mt] = *(const s16x8*)(&sA[(mt * 16 + l16) * 64 + pc * 8]);
                #pragma unroll
                for (int nt = 0; nt < 2; nt++)
                    bf[nt] = *(const s16x8*)(&sW[(w * 32 + nt * 16 + l16) * 64 + pc * 8]);
                #pragma unroll
                for (int mt = 0; mt < 4; mt++)
                    #pragma unroll
                    for (int nt = 0; nt < 2; nt++)
                        acc1[mt][nt] = __builtin_amdgcn_mfma_f32_16x16x32_bf16(
                            bf[nt], af[mt], acc1[mt][nt], 0, 0, 0);
            }
        }
        // ---- H epilogue: bias + relu + bf16 -> swizzled sH ----
        __syncthreads();
        {
            const float* bb1 = p.b1 + (long)z * 512 + c * 128;
            #pragma unroll
            for (int mt = 0; mt < 4; mt++) {
                int r = mt * 16 + l16;
                #pragma unroll
                for (int nt = 0; nt < 2; nt++) {
                    int col = w * 32 + nt * 16 + q * 4;
                    float4 bv = *(const float4*)(bb1 + col);
                    f32x4 v = acc1[mt][nt];
                    u16x4 o;
                    o.x = f2bf(fmaxf(v.x + bv.x, 0.f));
                    o.y = f2bf(fmaxf(v.y + bv.y, 0.f));
                    o.z = f2bf(fmaxf(v.z + bv.z, 0.f));
                    o.w = f2bf(fmaxf(v.w + bv.w, 0.f));
                    int c8 = col >> 3;
                    *(u16x4*)(&sH[r * 128 + ((c8 ^ (r & 7)) << 3) + (q & 1) * 4]) = o;
                }
            }
        }
        // ---- stage 2: acc += H_c @ W2[c*128 .. , :] ----
        #pragma unroll
        for (int s = 0; s < 2; s++) {
            __syncthreads();
            #pragma unroll
            for (int i = 0; i < 8; i++)
                load_lds16(W2b + (long)(32 * i + tr) * 512 + c * 128 + s * 64 + lc * 8,
                           &sW[i * 2048 + ldst]);
            __syncthreads();
            #pragma unroll
            for (int kk = 0; kk < 2; kk++) {
                const int kg = s * 8 + ((kk << 2) | q);
                const int pc = ((kk << 2) | q) ^ key;
                s16x8 af[4], bf[4];
                #pragma unroll
                for (int mt = 0; mt < 4; mt++) {
                    int r = mt * 16 + l16;
                    af[mt] = *(const s16x8*)(&sH[r * 128 + ((kg ^ key) << 3)]);
                }
                #pragma unroll
                for (int nt = 0; nt < 4; nt++)
                    bf[nt] = *(const s16x8*)(&sW[(w * 64 + nt * 16 + l16) * 64 + pc * 8]);
                #pragma unroll
                for (int mt = 0; mt < 4; mt++)
                    #pragma unroll
                    for (int nt = 0; nt < 4; nt++)
                        acc[mt][nt] = __builtin_amdgcn_mfma_f32_16x16x32_bf16(
                            bf[nt], af[mt], acc[mt][nt], 0, 0, 0);
            }
        }
    }

    // ---- O epilogue ----
    const float* bb2 = p.b2 + (long)z * 256;
    u16* Op = p.O + (long)z * BATCH * 256;
    #pragma unroll
    for (int mt = 0; mt < 4; mt++) {
        int grow = m0 + mt * 16 + l16;
        u16* rowp = Op + (long)grow * 256;
        #pragma unroll
        for (int nt = 0; nt < 4; nt++) {
            int gc = w * 64 + nt * 16 + q * 4;
            float4 bv = *(const float4*)(bb2 + gc);
            f32x4 v = acc[mt][nt];
            v.x = fmaxf(v.x + bv.x, 0.f);
            v.y = fmaxf(v.y + bv.y, 0.f);
            v.z = fmaxf(v.z + bv.z, 0.f);
            v.w = fmaxf(v.w + bv.w, 0.f);
            u16x4 o;
            o.x = f2bf(v.x); o.y = f2bf(v.y); o.z = f2bf(v.z); o.w = f2bf(v.w);
            *(u16x4*)(rowp + gc) = o;
        }
    }
}

__global__ __launch_bounds__(256, 2) void fused_l1(FusedP p) { expert_impl(p); }
__global__ __launch_bounds__(256, 2) void fused_l2(FusedP p) { expert_impl(p); }

// ---------------------------------------------------------------------------
// Fused towers (unchanged)
// ---------------------------------------------------------------------------
__global__ __launch_bounds__(256, 1)
void tower_fused(const u16* __restrict__ x2, const u16* __restrict__ W1t,
                 const float* __restrict__ b1, const u16* __restrict__ W2t,
                 const float* __restrict__ b2, float* __restrict__ out) {
    const int t = blockIdx.y, m0 = blockIdx.x * 64;
    __shared__ u16 sX[64 * 256];
    __shared__ u16 sW1[128 * 256];
    __shared__ u16 sH[64 * 136];
    __shared__ u16 sW2[64 * 128];
    __shared__ float sB1[128];
    __shared__ float sB2[64];
    const int tid = threadIdx.x, lane = tid & 63, w = tid >> 6;
    const int l16 = lane & 15, q = lane >> 4;

    #pragma unroll
    for (int i = 0; i < 8; i++) {
        int c = i * 256 + tid, row = c >> 5, kc = c & 31;
        int lcc = (kc & ~7) | ((kc & 7) ^ (row & 7));
        load_lds16(x2 + ((long)t * BATCH + m0 + row) * 256 + lcc * 8,
                   &sX[(i * 256 + (tid & ~63)) * 8]);
    }
    #pragma unroll
    for (int i = 0; i < 16; i++) {
        int c = i * 256 + tid, row = c >> 5, kc = c & 31;
        int lcc = (kc & ~7) | ((kc & 7) ^ (row & 7));
        load_lds16(W1t + ((long)t * 128 + row) * 256 + lcc * 8,
                   &sW1[(i * 256 + (tid & ~63)) * 8]);
    }
    #pragma unroll
    for (int i = 0; i < 4; i++) {
        int c = i * 256 + tid, row = c >> 4, kc = c & 15;
        int lcc = (kc & ~7) | ((kc & 7) ^ (row & 7));
        load_lds16(W2t + ((long)t * 64 + row) * 128 + lcc * 8,
                   &sW2[(i * 256 + (tid & ~63)) * 8]);
    }
    if (tid < 128) sB1[tid] = b1[t * 128 + tid];
    if (tid < 64)  sB2[tid] = b2[t * 64 + tid];
    __syncthreads();

    f32x4 acc1[4][2] = {};
    #pragma unroll
    for (int kk = 0; kk < 8; kk++) {
        int pcb = kk * 4 + q;
        s16x8 af[4], bf[2];
        #pragma unroll
        for (int mt = 0; mt < 4; mt++) {
            int row = mt * 16 + l16;
            int sc = (pcb & ~7) | ((pcb & 7) ^ (row & 7));
            af[mt] = *(const s16x8*)(&sX[row * 256 + sc * 8]);
        }
        #pragma unroll
        for (int nt = 0; nt < 2; nt++) {
            int row = w * 32 + nt * 16 + l16;
            int sc = (pcb & ~7) | ((pcb & 7) ^ (row & 7));
            bf[nt] = *(const s16x8*)(&sW1[row * 256 + sc * 8]);
        }
        #pragma unroll
        for (int mt = 0; mt < 4; mt++)
            #pragma unroll
            for (int nt = 0; nt < 2; nt++)
                acc1[mt][nt] = __builtin_amdgcn_mfma_f32_16x16x32_bf16(
                    bf[nt], af[mt], acc1[mt][nt], 0, 0, 0);
    }
    #pragma unroll
    for (int mt = 0; mt < 4; mt++) {
        int row = mt * 16 + l16;
        #pragma unroll
        for (int nt = 0; nt < 2; nt++) {
            int col = w * 32 + nt * 16 + q * 4;
            f32x4 v = acc1[mt][nt];
            u16x4 o;
            o.x = f2bf(fmaxf(v.x + sB1[col + 0], 0.f));
            o.y = f2bf(fmaxf(v.y + sB1[col + 1], 0.f));
            o.z = f2bf(fmaxf(v.z + sB1[col + 2], 0.f));
            o.w = f2bf(fmaxf(v.w + sB1[col + 3], 0.f));
            *(u16x4*)(&sH[row * 136 + col]) = o;
        }
    }
    __syncthreads();

    f32x4 acc2[4] = {};
    #pragma unroll
    for (int kk = 0; kk < 4; kk++) {
        s16x8 af[4], bf;
        #pragma unroll
        for (int mt = 0; mt < 4; mt++) {
            int row = mt * 16 + l16;
            af[mt] = *(const s16x8*)(&sH[row * 136 + kk * 32 + q * 8]);
        }
        {
            int row = w * 16 + l16;
            int pc = kk * 4 + q;
            int sc = (pc & ~7) | ((pc & 7) ^ (row & 7));
            bf = *(const s16x8*)(&sW2[row * 128 + sc * 8]);
        }
        #pragma unroll
        for (int mt = 0; mt < 4; mt++)
            acc2[mt] = __builtin_amdgcn_mfma_f32_16x16x32_bf16(
                bf, af[mt], acc2[mt], 0, 0, 0);
    }
    #pragma unroll
    for (int mt = 0; mt < 4; mt++) {
        int grow = m0 + mt * 16 + l16;
        int col = w * 16 + q * 4;
        float4 bv = *(const float4*)(sB2 + col);
        f32x4 v = acc2[mt];
        float4 r;
        r.x = 1.f / (1.f + __expf(-(v.x + bv.x)));
        r.y = 1.f / (1.f + __expf(-(v.y + bv.y)));
        r.z = 1.f / (1.f + __expf(-(v.z + bv.z)));
        r.w = 1.f / (1.f + __expf(-(v.w + bv.w)));
        *(float4*)(out + (long)grow * 128 + t * 64 + col) = r;
    }
}

// ---------------------------------------------------------------------------
// Level-1 fused gates+combine. COALESCED weight access: lane-fast k
// (k = u*32 + l) so each float4/float2 weight load is lane-consecutive
// (16B stride -> 8 lines/wave instead of 64). Same k-partition sum.
// ---------------------------------------------------------------------------
__global__ __launch_bounds__(256)
void gate1(const u16* __restrict__ embed, const u16* __restrict__ out1,
           const float* __restrict__ g1Ws, const float* __restrict__ g1bs,
           const float* __restrict__ gWsh, const float* __restrict__ gbsh,
           u16* __restrict__ x1) {
    const int m0 = blockIdx.x * 8;
    __shared__ float sg[8][16];
    const int tid = threadIdx.x;
    const int row = tid >> 5, l = tid & 31;
    const long rb = m0 + row;

    float a[4] = {0,0,0,0}, b[4] = {0,0,0,0}, c[6] = {0,0,0,0,0,0};
    {
        const u16* er = embed + rb * 512;
        #pragma unroll
        for (int u = 0; u < 16; u++) {
            int k = u * 32 + l;                       // lane-fast: coalesced
            float xv = bf2f(er[k]);
            float4 wa = *(const float4*)(g1Ws + k * 4);
            float4 wb = *(const float4*)(g1Ws + 2048 + k * 4);
            a[0] += xv * wa.x; a[1] += xv * wa.y; a[2] += xv * wa.z; a[3] += xv * wa.w;
            b[0] += xv * wb.x; b[1] += xv * wb.y; b[2] += xv * wb.z; b[3] += xv * wb.w;
            float2 w0 = *(const float2*)(gWsh + k * 6);
            float2 w1 = *(const float2*)(gWsh + k * 6 + 2);
            float2 w2 = *(const float2*)(gWsh + k * 6 + 4);
            c[0] += xv * w0.x; c[1] += xv * w0.y;
            c[2] += xv * w1.x; c[3] += xv * w1.y;
            c[4] += xv * w2.x; c[5] += xv * w2.y;
        }
    }
    #pragma unroll
    for (int off = 1; off < 32; off <<= 1) {
        #pragma unroll
        for (int g = 0; g < 4; g++) { a[g] += __shfl_xor(a[g], off); b[g] += __shfl_xor(b[g], off); }
        #pragma unroll
        for (int g = 0; g < 6; g++) c[g] += __shfl_xor(c[g], off);
    }
    if (l == 0) {
        float mx, s, e[6];
        mx = -1e30f;
        for (int g = 0; g < 4; g++) { a[g] += g1bs[g]; mx = fmaxf(mx, a[g]); }
        s = 0.f; for (int g = 0; g < 4; g++) { e[g] = __expf(a[g] - mx); s += e[g]; }
        for (int g = 0; g < 4; g++) sg[row][g] = e[g] / s;
        mx = -1e30f;
        for (int g = 0; g < 4; g++) { b[g] += g1bs[4 + g]; mx = fmaxf(mx, b[g]); }
        s = 0.f; for (int g = 0; g < 4; g++) { e[g] = __expf(b[g] - mx); s += e[g]; }
        for (int g = 0; g < 4; g++) sg[row][4 + g] = e[g] / s;
        mx = -1e30f;
        for (int g = 0; g < 6; g++) { c[g] += gbsh[g]; mx = fmaxf(mx, c[g]); }
        s = 0.f; for (int g = 0; g < 6; g++) { e[g] = __expf(c[g] - mx); s += e[g]; }
        for (int g = 0; g < 6; g++) sg[row][8 + g] = e[g] / s;
    }
    __syncthreads();

    const int c8 = l * 8;
    const u16* ob = out1 + rb * 256 + c8;
    u16x8 o[6];
    #pragma unroll
    for (int k = 0; k < 6; k++) o[k] = *(const u16x8*)(ob + (long)k * BATCH * 256);
    const float* g = sg[row];
    u16x8 r0, r1, r2;
    #pragma unroll
    for (int u = 0; u < 8; u++) {
        float o0 = bf2f(o[0][u]), o1 = bf2f(o[1][u]), o2 = bf2f(o[2][u]);
        float o3 = bf2f(o[3][u]), o4 = bf2f(o[4][u]), o5 = bf2f(o[5][u]);
        r0[u] = f2bf(g[0] * o0 + g[1] * o1 + g[2] * o4 + g[3] * o5);
        r1[u] = f2bf(g[4] * o2 + g[5] * o3 + g[6] * o4 + g[7] * o5);
        r2[u] = f2bf(g[8] * o0 + g[9] * o1 + g[10] * o2 + g[11] * o3 + g[12] * o4 + g[13] * o5);
    }
    *(u16x8*)(x1 + ((long)0 * BATCH + rb) * 256 + c8) = r0;
    *(u16x8*)(x1 + ((long)1 * BATCH + rb) * 256 + c8) = r1;
    *(u16x8*)(x1 + ((long)2 * BATCH + rb) * 256 + c8) = r2;
}

// ---------------------------------------------------------------------------
// Level-2 fused gates+combine. Same coalesced lane-fast-k weight access.
// ---------------------------------------------------------------------------
__global__ __launch_bounds__(256)
void gate2(const u16* __restrict__ x1, const u16* __restrict__ out2,
           const float* __restrict__ g2Ws, const float* __restrict__ g2bs,
           u16* __restrict__ x2) {
    const int m0 = blockIdx.x * 8;
    __shared__ float sg[8][8];
    const int tid = threadIdx.x;
    const int row = tid >> 5, l = tid & 31;
    const long rb = m0 + row;

    float a[4] = {0,0,0,0}, b[4] = {0,0,0,0};
    {
        const u16* e0 = x1 + rb * 256;
        const u16* e1 = e0 + (long)BATCH * 256;
        #pragma unroll
        for (int u = 0; u < 8; u++) {
            int k = u * 32 + l;                       // lane-fast: coalesced
            float xv0 = bf2f(e0[k]);
            float xv1 = bf2f(e1[k]);
            float4 wa = *(const float4*)(g2Ws + k * 4);
            float4 wb = *(const float4*)(g2Ws + 1024 + k * 4);
            a[0] += xv0 * wa.x; a[1] += xv0 * wa.y; a[2] += xv0 * wa.z; a[3] += xv0 * wa.w;
            b[0] += xv1 * wb.x; b[1] += xv1 * wb.y; b[2] += xv1 * wb.z; b[3] += xv1 * wb.w;
        }
    }
    #pragma unroll
    for (int off = 1; off < 32; off <<= 1) {
        #pragma unroll
        for (int g = 0; g < 4; g++) { a[g] += __shfl_xor(a[g], off); b[g] += __shfl_xor(b[g], off); }
    }
    if (l == 0) {
        float mx, s, e[4];
        mx = -1e30f;
        for (int g = 0; g < 4; g++) { a[g] += g2bs[g]; mx = fmaxf(mx, a[g]); }
        s = 0.f; for (int g = 0; g < 4; g++) { e[g] = __expf(a[g] - mx); s += e[g]; }
        for (int g = 0; g < 4; g++) sg[row][g] = e[g] / s;
        mx = -1e30f;
        for (int g = 0; g < 4; g++) { b[g] += g2bs[4 + g]; mx = fmaxf(mx, b[g]); }
        s = 0.f; for (int g = 0; g < 4; g++) { e[g] = __expf(b[g] - mx); s += e[g]; }
        for (int g = 0; g < 4; g++) sg[row][4 + g] = e[g] / s;
    }
    __syncthreads();

    const int c8 = l * 8;
    const u16* ob = out2 + rb * 256 + c8;
    u16x8 o[6];
    #pragma unroll
    for (int k = 0; k < 6; k++) o[k] = *(const u16x8*)(ob + (long)k * BATCH * 256);
    const float* g = sg[row];
    u16x8 r0, r1;
    #pragma unroll
    for (int u = 0; u < 8; u++) {
        float o0 = bf2f(o[0][u]), o1 = bf2f(o[1][u]), o2 = bf2f(o[2][u]);
        float o3 = bf2f(o[3][u]), o4 = bf2f(o[4][u]), o5 = bf2f(o[5][u]);
        r0[u] = f2bf(g[0] * o0 + g[1] * o1 + g[2] * o4 + g[3] * o5);
        r1[u] = f2bf(g[4] * o2 + g[5] * o3 + g[6] * o4 + g[7] * o5);
    }
    *(u16x8*)(x2 + ((long)0 * BATCH + rb) * 256 + c8) = r0;
    *(u16x8*)(x2 + ((long)1 * BATCH + rb) * 256 + c8) = r1;
}

// ---------------------------------------------------------------------------
extern "C" void kernel_launch(void* const* d_in, const int* in_sizes, int n_in,
                              void* d_out, int out_size, void* d_ws, size_t ws_size,
                              hipStream_t stream) {
    const int*   x_ids = (const int*)  d_in[0];
    const float* emb   = (const float*)d_in[1];
    const float* e1W1  = (const float*)d_in[2];
    const float* e1b1  = (const float*)d_in[3];
    const float* e1W2  = (const float*)d_in[4];
    const float* e1b2  = (const float*)d_in[5];
    const float* g1Ws  = (const float*)d_in[6];
    const float* g1bs  = (const float*)d_in[7];
    const float* g1Wsh = (const float*)d_in[8];
    const float* g1bsh = (const float*)d_in[9];
    const float* e2W1  = (const float*)d_in[10];
    const float* e2b1  = (const float*)d_in[11];
    const float* e2W2  = (const float*)d_in[12];
    const float* e2b2  = (const float*)d_in[13];
    const float* g2Ws  = (const float*)d_in[14];
    const float* g2bs  = (const float*)d_in[15];
    const float* twW1  = (const float*)d_in[16];
    const float* twb1  = (const float*)d_in[17];
    const float* twW2  = (const float*)d_in[18];
    const float* twb2  = (const float*)d_in[19];
    float* out = (float*)d_out;

    char* ws = (char*)d_ws;
    u16* embed   = (u16*)(ws + 0);                       // [B,512]
    u16* wt_e1W1 = (u16*)(ws + 16777216);                // [6,512,512]
    u16* wt_e1W2 = (u16*)(ws + 19922944);                // [6,256,512]
    u16* wt_e2W1 = (u16*)(ws + 21495808);                // [6,512,256]
    u16* wt_e2W2 = (u16*)(ws + 23068672);                // [6,256,512]
    u16* wt_twW1 = (u16*)(ws + 24641536);                // [2,128,256]
    u16* wt_twW2 = (u16*)(ws + 24772608);                // [2,64,128]
    u16* o_buf   = (u16*)(ws + 125468672);               // [6,B,256]
    u16* x1      = (u16*)(ws + 175800320);               // [3,B,256]
    u16* x2      = (u16*)(ws + 200966144);               // [2,B,256]

    PrepArgs pa;
    pa.d[0] = { e1W1, wt_e1W1, 512, 512, 6,  0 };
    pa.d[1] = { e1W2, wt_e1W2, 512, 256, 6,  6 };
    pa.d[2] = { e2W1, wt_e2W1, 256, 512, 6, 12 };
    pa.d[3] = { e2W2, wt_e2W2, 512, 256, 6, 18 };
    pa.d[4] = { twW1, wt_twW1, 256, 128, 2, 24 };
    pa.d[5] = { twW2, wt_twW2, 128,  64, 2, 26 };
    prep_weights<<<dim3(16, 16, 28), 256, 0, stream>>>(pa);

    gather_embed<<<dim3(BATCH * NFEAT * 4 / 256), 256, 0, stream>>>(x_ids, emb, embed);

    // Level 1: fused two-layer experts (A = embed, shared across z)
    FusedP f1 = { embed, wt_e1W1, e1b1, wt_e1W2, e1b2, o_buf, 512, 3, 0L };
    fused_l1<<<dim3(BATCH / 64, 1, 6), 256, 0, stream>>>(f1);

    gate1<<<dim3(BATCH / 8), 256, 0, stream>>>(embed, o_buf, g1Ws, g1bs, g1Wsh, g1bsh, x1);

    // Level 2: fused two-layer experts (A = x1[z>>1])
    FusedP f2 = { x1, wt_e2W1, e2b1, wt_e2W2, e2b2, o_buf, 256, 1, (long)BATCH * 256 };
    fused_l2<<<dim3(BATCH / 64, 1, 6), 256, 0, stream>>>(f2);

    gate2<<<dim3(BATCH / 8), 256, 0, stream>>>(x1, o_buf, g2Ws, g2bs, x2);

    tower_fused<<<dim3(BATCH / 64, 2), 256, 0, stream>>>(x2, wt_twW1, twb1, wt_twW2, twb2, out);
}